// Round 5
// baseline (693.809 us; speedup 1.0000x reference)
//
#include <hip/hip_runtime.h>
#include <hip/hip_bf16.h>
#include <stdint.h>

typedef __attribute__((ext_vector_type(8))) __bf16 bf16x8;
typedef __attribute__((ext_vector_type(4))) float f32x4;
typedef __attribute__((ext_vector_type(2))) float f32x2;
typedef __attribute__((ext_vector_type(4))) unsigned uint4v;
typedef __attribute__((ext_vector_type(2))) unsigned uint2v;

union U4 { uint4v u; bf16x8 b; };

// ---- d_ws layout (bytes) ----
#define WS_WDEV_H 0
#define WS_WDEV_L 4096
#define WS_W1_H   8192
#define WS_W1_L   16384
#define WS_W2_H   24576
#define WS_W2_L   32768
#define WS_W3_H   40960
#define WS_W3_L   49152
#define WS_WA_H   57344
#define WS_WA_L   73728
#define WS_WF_H   90112
#define WS_WF_L   122880
// total 155648 bytes

__device__ __forceinline__ unsigned short f2bf(float f){
  union { float f; unsigned u; } v; v.f = f;
  unsigned r = v.u + 0x7fffu + ((v.u >> 16) & 1u);
  return (unsigned short)(r >> 16);
}
__device__ __forceinline__ float bf2f(unsigned short h){
  union { unsigned u; float f; } v; v.u = ((unsigned)h) << 16; return v.f;
}
__device__ __forceinline__ void split2(float x, unsigned short& hi, unsigned short& lo){
  hi = f2bf(x);
  lo = f2bf(x - bf2f(hi));   // exact residual
}
__device__ __forceinline__ f32x4 mfma16(const U4& a, const U4& b, f32x4 c){
  return __builtin_amdgcn_mfma_f32_16x16x32_bf16(a.b, b.b, c, 0, 0, 0);
}

// ---- HW packed bf16 conversion (v_cvt_pk_bf16_f32, RNE — bit-identical to rnu) ----
__device__ __forceinline__ unsigned cvt_pk_bf(float a, float b){
  float2 p; p.x = a; p.y = b;
  union { __hip_bfloat162 h; unsigned u; } cv;
  cv.h = __float22bfloat162_rn(p);          // low16 = bf(a), high16 = bf(b)
  return cv.u;
}
// R11: packed-residual split. hi2 = (bf16(y)<<16)|bf16(x), lo2 = residuals.
// The residual subtraction is a <2 x float> op -> v_pk_add_f32 (neg) on gfx950.
// Bit-identical to the scalar version (same IEEE ops).
__device__ __forceinline__ void split_pair2(f32x2 xy, unsigned& hi2, unsigned& lo2){
  hi2 = cvt_pk_bf(xy.x, xy.y);
  f32x2 b;
  b.x = __uint_as_float(hi2 << 16);
  b.y = __uint_as_float(hi2 & 0xffff0000u);
  f32x2 r = xy - b;                         // packed sub
  lo2 = cvt_pk_bf(r.x, r.y);
}
// (lo16<<16)|hi16 for one value (head zbuf element format)
__device__ __forceinline__ unsigned pack_hl(float z){
  unsigned h = cvt_pk_bf(z, 0.f) & 0xffffu;
  float r = z - __uint_as_float(h << 16);
  return (cvt_pk_bf(0.f, r) & 0xffff0000u) | h;
}

// ------------------------------------------------------------------
// prep kernel: weights -> hi/lo bf16 MFMA B-fragments.
// B-frag: idx = ((ks*NT+nt)*64 + lane)*8 + j ; k = ks*32+(lane>>4)*8+j, n = nt*16+(lane&15)
// ------------------------------------------------------------------
extern "C" __global__ void prep_weights(const float* __restrict__ Wdev,
                                        const float* __restrict__ W1,
                                        const float* __restrict__ W2,
                                        const float* __restrict__ W3,
                                        const float* __restrict__ Wf1,
                                        char* __restrict__ ws)
{
  unsigned short* WdevH = (unsigned short*)(ws + WS_WDEV_H);
  unsigned short* WdevL = (unsigned short*)(ws + WS_WDEV_L);
  unsigned short* WH[3] = {(unsigned short*)(ws+WS_W1_H),(unsigned short*)(ws+WS_W2_H),(unsigned short*)(ws+WS_W3_H)};
  unsigned short* WL[3] = {(unsigned short*)(ws+WS_W1_L),(unsigned short*)(ws+WS_W2_L),(unsigned short*)(ws+WS_W3_L)};
  unsigned short* WaH = (unsigned short*)(ws + WS_WA_H);
  unsigned short* WaL = (unsigned short*)(ws + WS_WA_L);
  unsigned short* WfH = (unsigned short*)(ws + WS_WF_H);
  unsigned short* WfL = (unsigned short*)(ws + WS_WF_L);
  const int total = 2048 + 3*4096 + 8192 + 16384;
  for (int idx = blockIdx.x*256 + threadIdx.x; idx < total; idx += gridDim.x*256){
    if (idx < 2048){                       // Wdev (14x64), K padded to 32, NT=4
      int tt = idx;
      int frag = tt >> 9, within = tt & 511, lane = within >> 3, j = within & 7;
      int nt = frag & 3;
      int k = ((lane>>4)<<3) + j;
      int n = (nt<<4) + (lane & 15);
      float v = (k < 14) ? Wdev[k*64 + n] : 0.f;
      unsigned short h,l; split2(v,h,l); WdevH[tt]=h; WdevL[tt]=l;
    } else if (idx < 2048 + 3*4096){       // W1/W2/W3 (64x64), KS=2, NT=4
      int tt = idx - 2048; int Li = tt / 4096; int r = tt - Li*4096;
      int frag = r >> 9, within = r & 511, lane = within >> 3, j = within & 7;
      int ks = frag >> 2, nt = frag & 3;
      int k = (ks<<5) + ((lane>>4)<<3) + j;
      int n = (nt<<4) + (lane & 15);
      const float* W = (Li==0) ? W1 : ((Li==1) ? W2 : W3);
      float v = W[k*64 + n];
      unsigned short h,l; split2(v,h,l); WH[Li][r]=h; WL[Li][r]=l;
    } else if (idx < 2048 + 3*4096 + 8192){ // Wa = Wf1 rows 0..63 (64x128), KS=2, NT=8
      int r = idx - (2048 + 3*4096);
      int frag = r >> 9, within = r & 511, lane = within >> 3, j = within & 7;
      int ks = frag >> 3, nt = frag & 7;
      int k = (ks<<5) + ((lane>>4)<<3) + j;
      int n = (nt<<4) + (lane & 15);
      float v = Wf1[k*128 + n];
      unsigned short h,l; split2(v,h,l); WaH[r]=h; WaL[r]=l;
    } else {                                // Wfull = Wf1 rows 64..191 (128x128), KS=4, NT=8
      int r = idx - (2048 + 3*4096 + 8192);
      int frag = r >> 9, within = r & 511, lane = within >> 3, j = within & 7;
      int ks = frag >> 3, nt = frag & 7;
      int k = (ks<<5) + ((lane>>4)<<3) + j;
      int n = (nt<<4) + (lane & 15);
      float v = Wf1[(64 + k)*128 + n];
      unsigned short h,l; split2(v,h,l); WfH[r]=h; WfL[r]=l;
    }
  }
}

// ------------------------------------------------------------------
// fused PGCN critic. R10 register diet + R11 VOP3P packed-f32 VALU diet:
//   - all pairwise f32 math (d-scaling, bias adds, split residuals,
//     head epilogue relu*w2 accumulate) expressed as f32x2 vector ops ->
//     v_pk_add/mul/fma_f32 (2 f32/instr, bit-identical IEEE)
//   - fmax stays scalar (no packed max f32 on CDNA)
//   - structure/barriers/LDS identical to R10 (346 us, no spills)
// ------------------------------------------------------------------
extern "C" __global__ __launch_bounds__(256, 6)
void pgcn_fused(const float* __restrict__ dobs, const float* __restrict__ sobs,
                const float* __restrict__ adj,
                const float* __restrict__ bdev,
                const float* __restrict__ Wsrv, const float* __restrict__ bsrv,
                const float* __restrict__ b1, const float* __restrict__ b2,
                const float* __restrict__ b3,
                const float* __restrict__ bf1, const float* __restrict__ Wf2,
                const float* __restrict__ bf2,
                const char* __restrict__ ws, float* __restrict__ out)
{
  // hi plane: halfwords [0, 4608)  (64 rows x 72), lo plane: [4608, 9216); 18432 B
  __shared__ __align__(16) unsigned short     lds_Yr[9216];
  __shared__ __align__(16) unsigned long long lds_Abits[64];   // LIVE all layers
  __shared__ __align__(16) float    lds_d[64];                  // dead by head
  // ---- head-phase aliases (live only after the last GCN barrier) ----
  char* Yb = (char*)lds_Yr;
  float*          lds_mp  = (float*)(Yb + 16384);               // 1024 B
  float*          lds_srv = (float*)(Yb + 17408);               //  256 B
  float*          lds_s1  = (float*)(Yb + 17664);               //  512 B
  unsigned short* lds_Vl  = (unsigned short*)(Yb + 18176);      //  256 B
  unsigned short* lds_Vh  = (unsigned short*)lds_d;             //  256 B

  const int t = threadIdx.x;
  const int w = t >> 6;
  const int lane = t & 63;
  const int quad = lane >> 4;
  const int c = lane & 15;
  const long item = blockIdx.x;
  const bool isSrv = (w == 3) && (quad == 3);

  // ---------- stage adjacency as bitmask ----------
  {
    const f32x4* src = (const f32x4*)(adj + item*4096 + ((t>>2)<<6) + ((t&3)<<4));
    unsigned bits = 0;
    for (int i = 0; i < 4; ++i){
      f32x4 v = src[i];
      unsigned b = (v.x != 0.f) | (((unsigned)(v.y != 0.f))<<1)
                 | (((unsigned)(v.z != 0.f))<<2) | (((unsigned)(v.w != 0.f))<<3);
      bits |= b << (i<<2);
    }
    ((unsigned short*)lds_Abits)[t] = (unsigned short)bits;
  }

  // ---------- load device_obs rows as A-operand frags (hi/lo) ----------
  unsigned ahi[4] = {0,0,0,0}, alo[4] = {0,0,0,0};
  {
    int m = (w<<4) + c;
    if (quad < 2 && m < 63){
      const float* rp = dobs + item*882 + m*14 + (quad<<3);
      float e[8];
      f32x2 p0 = *(const f32x2*)(rp);
      f32x2 p1 = *(const f32x2*)(rp+2);
      f32x2 p2 = *(const f32x2*)(rp+4);
      e[0]=p0.x; e[1]=p0.y; e[2]=p1.x; e[3]=p1.y; e[4]=p2.x; e[5]=p2.y;
      if (quad == 0){
        f32x2 p3 = *(const f32x2*)(rp+6);
        e[6]=p3.x; e[7]=p3.y;
      } else {
        e[6]=0.f; e[7]=0.f;                   // k = 14,15 pad
      }
      for (int d0 = 0; d0 < 4; ++d0){
        f32x2 ep; ep.x = e[2*d0]; ep.y = e[2*d0+1];
        split_pair2(ep, ahi[d0], alo[d0]);
      }
    }
  }

  // ---------- early hoisted per-thread constants ----------
  float bdv0 = bdev[c], bdv1 = bdev[c+16], bdv2 = bdev[c+32], bdv3 = bdev[c+48];
  float srvv4[4];
  if (isSrv){
    float s0 = sobs[item*3+0], s1a = sobs[item*3+1], s2a = sobs[item*3+2];
#pragma unroll
    for (int nt = 0; nt < 4; ++nt){
      int col = c + (nt<<4);
      float v = s0*Wsrv[col] + s1a*Wsrv[64+col] + s2a*Wsrv[128+col] + bsrv[col];
      srvv4[nt] = fmaxf(v, 0.f);
    }
  }
  __syncthreads();   // [S1] bits ready

  // ---------- degrees from popcount ----------
  if (t < 64){
    unsigned long long mk = lds_Abits[t];
    int deg = __popcll(mk);
    lds_d[t] = 1.0f / sqrtf((float)(deg < 1 ? 1 : deg));
  }
  __syncthreads();   // [S2] d ready

  // LDS base offsets (bytes)
  const int ybw = (c*72 + (w<<4) + (quad<<2)) << 1;          // Y write (+2304*nt)
  const int yrd = (c*72 + (quad<<3)) << 1;                    // Y read  (+2304*mt+64*ks)
  const int zbw = (((w<<4)+c)*72 + (quad<<2)) << 1;           // Z write (+32*mt)
  const int zrd = (((w<<4)+c)*72 + (quad<<3)) << 1;           // Z read  (+64*ks)

  float hcur[4][4];

  // ---------- embed: x = relu(dobs@Wdev + bdev); row63 = server; write Y1 = d*x
  {
    f32x4 dE = *(const f32x4*)&lds_d[(w<<4) + (quad<<2)];
    f32x2 dE01, dE23;
    dE01.x = dE.x; dE01.y = dE.y; dE23.x = dE.z; dE23.y = dE.w;
    U4 a_h, a_l;
    a_h.u = uint4v{ahi[0],ahi[1],ahi[2],ahi[3]};
    a_l.u = uint4v{alo[0],alo[1],alo[2],alo[3]};
    const uint4v* WdHp = (const uint4v*)(ws + WS_WDEV_H);
    const uint4v* WdLp = (const uint4v*)(ws + WS_WDEV_L);
#define EMB(NT, BB) { \
    U4 wh, wl; \
    wh.u = WdHp[(NT)*64 + lane]; wl.u = WdLp[(NT)*64 + lane]; \
    f32x4 g = {0.f,0.f,0.f,0.f}; \
    g = mfma16(a_h, wh, g); \
    g = mfma16(a_h, wl, g); \
    g = mfma16(a_l, wh, g); \
    f32x2 bbv; bbv.x = (BB); bbv.y = (BB); \
    f32x2 y01, y23; \
    y01.x = g[0]; y01.y = g[1]; y23.x = g[2]; y23.y = g[3]; \
    y01 += bbv; y23 += bbv;                       /* pk_add */ \
    y01.x = fmaxf(y01.x, 0.f); y01.y = fmaxf(y01.y, 0.f); \
    y23.x = fmaxf(y23.x, 0.f); y23.y = fmaxf(y23.y, 0.f); \
    if (isSrv) y23.y = srvv4[NT];            /* node 63 = server embedding */ \
    y01 *= dE01; y23 *= dE23;                     /* pk_mul: Y = d * x */ \
    unsigned h01,l01,h23,l23; \
    split_pair2(y01, h01, l01); \
    split_pair2(y23, h23, l23); \
    *(uint2v*)(Yb + ybw + 2304*(NT))        = uint2v{ h01, h23 }; \
    *(uint2v*)(Yb + ybw + 2304*(NT) + 9216) = uint2v{ l01, l23 }; }
    EMB(0, bdv0)
    EMB(1, bdv1)
    EMB(2, bdv2)
    EMB(3, bdv3)
#undef EMB
  }
  __syncthreads();   // Y1 ready

  // ---------- 3 GCN layers ----------
  const uint4v* WH_tab[3] = {(const uint4v*)(ws+WS_W1_H),(const uint4v*)(ws+WS_W2_H),(const uint4v*)(ws+WS_W3_H)};
  const uint4v* WL_tab[3] = {(const uint4v*)(ws+WS_W1_L),(const uint4v*)(ws+WS_W2_L),(const uint4v*)(ws+WS_W3_L)};
  const float* bias_tab[3] = {b1, b2, b3};

  for (int L = 0; L < 3; ++L){
    const uint4v* WHp = WH_tab[L];
    const uint4v* WLp = WL_tab[L];
    const float* bp = bias_tab[L];
    float bL0 = bp[c], bL1 = bp[c+16], bL2 = bp[c+32], bL3 = bp[c+48];
    float ddc = lds_d[(w<<4) + c];

    // atk re-derived per layer from LIVE Abits — live range = step1 only
    U4 atk0, atk1;
    {
      unsigned long long mk = lds_Abits[(w<<4) + c];
      unsigned by0 = (unsigned)(mk >> (quad<<3)) & 0xffu;
      unsigned by1 = (unsigned)(mk >> (32 + (quad<<3))) & 0xffu;
#pragma unroll
      for (int r = 0; r < 4; ++r){
        unsigned e0 = 0u - ((by0 >> (2*r)) & 1u);
        unsigned o0 = 0u - ((by0 >> (2*r+1)) & 1u);
        atk0.u[r] = (e0 & 0x3f80u) | (o0 & 0x3f800000u);
        unsigned e1 = 0u - ((by1 >> (2*r)) & 1u);
        unsigned o1 = 0u - ((by1 >> (2*r+1)) & 1u);
        atk1.u[r] = (e1 & 0x3f80u) | (o1 & 0x3f800000u);
      }
    }

    // step 1 (swapped): Zt = Yt @ At, depth-2 pipeline over mt (LDS reads only)
    f32x4 zacc0, zacc1, zacc2, zacc3;
    {
      U4 yAh0,yAl0,yAh1,yAl1, yBh0,yBl0,yBh1,yBl1;
#define LOADY(H0,L0,H1,L1, MT) \
      H0.u = *(const uint4v*)(Yb + yrd + 2304*(MT)); \
      L0.u = *(const uint4v*)(Yb + yrd + 2304*(MT) + 9216); \
      H1.u = *(const uint4v*)(Yb + yrd + 2304*(MT) + 64); \
      L1.u = *(const uint4v*)(Yb + yrd + 2304*(MT) + 64 + 9216);
#define ZSTEP(ZD, H0,L0,H1,L1) { \
      f32x4 g = {0.f,0.f,0.f,0.f}; \
      g = mfma16(H0, atk0, g); \
      g = mfma16(L0, atk0, g); \
      g = mfma16(H1, atk1, g); \
      g = mfma16(L1, atk1, g); \
      ZD = g; }
      LOADY(yAh0,yAl0,yAh1,yAl1, 0)
      LOADY(yBh0,yBl0,yBh1,yBl1, 1)
      ZSTEP(zacc0, yAh0,yAl0,yAh1,yAl1)
      LOADY(yAh0,yAl0,yAh1,yAl1, 2)
      ZSTEP(zacc1, yBh0,yBl0,yBh1,yBl1)
      LOADY(yBh0,yBl0,yBh1,yBl1, 3)
      ZSTEP(zacc2, yAh0,yAl0,yAh1,yAl1)
      ZSTEP(zacc3, yBh0,yBl0,yBh1,yBl1)
#undef LOADY
#undef ZSTEP
    }
    __syncthreads();  // [B2] all Y reads done; region reusable

    // prefetch step-3 weights nt=0 NOW: L2 latency hides under step-2 LDS work
    U4 w0h, w0l, w1h, w1l;
    w0h.u = WHp[0*64 + lane];
    w0l.u = WLp[0*64 + lane];
    w1h.u = WHp[4*64 + lane];
    w1l.u = WLp[4*64 + lane];

    // step 2: Z' = d*Zt (pk_mul), regroup into per-wave rows (planes)
    {
      f32x2 dd2; dd2.x = ddc; dd2.y = ddc;
#define Z2(ZA, OFF) { \
      f32x2 p01, p23; \
      p01.x = ZA[0]; p01.y = ZA[1]; p23.x = ZA[2]; p23.y = ZA[3]; \
      p01 *= dd2; p23 *= dd2;                       /* pk_mul */ \
      unsigned h01,l01,h23,l23; \
      split_pair2(p01, h01, l01); \
      split_pair2(p23, h23, l23); \
      *(uint2v*)(Yb + zbw + (OFF))        = uint2v{ h01, h23 }; \
      *(uint2v*)(Yb + zbw + (OFF) + 9216) = uint2v{ l01, l23 }; }
      Z2(zacc0,  0)
      Z2(zacc1, 32)
      Z2(zacc2, 64)
      Z2(zacc3, 96)
#undef Z2
    }
    // wave-private rows: order LDS writes before reads WITHOUT draining vmcnt
    asm volatile("s_waitcnt lgkmcnt(0)" ::: "memory");
    U4 zh0, zl0, zh1, zl1;
    zh0.u = *(const uint4v*)(Yb + zrd);
    zl0.u = *(const uint4v*)(Yb + zrd + 9216);
    zh1.u = *(const uint4v*)(Yb + zrd + 64);
    zl1.u = *(const uint4v*)(Yb + zrd + 64 + 9216);

    // step 3: G = Z' @ W (3-pass split), h = relu(G + b); single W buffer
#define GSTEP(NT, BB) { \
    f32x4 g = {0.f,0.f,0.f,0.f}; \
    g = mfma16(zh0, w0h, g); g = mfma16(zh0, w0l, g); g = mfma16(zl0, w0h, g); \
    g = mfma16(zh1, w1h, g); g = mfma16(zh1, w1l, g); g = mfma16(zl1, w1h, g); \
    f32x2 bbv; bbv.x = (BB); bbv.y = (BB); \
    f32x2 t01, t23; \
    t01.x = g[0]; t01.y = g[1]; t23.x = g[2]; t23.y = g[3]; \
    t01 += bbv; t23 += bbv;                         /* pk_add */ \
    hcur[NT][0] = fmaxf(t01.x, 0.f); \
    hcur[NT][1] = fmaxf(t01.y, 0.f); \
    hcur[NT][2] = fmaxf(t23.x, 0.f); \
    hcur[NT][3] = fmaxf(t23.y, 0.f); }
#define LOADW(NT) \
    w0h.u = WHp[(NT)*64 + lane]; \
    w0l.u = WLp[(NT)*64 + lane]; \
    w1h.u = WHp[(4+(NT))*64 + lane]; \
    w1l.u = WLp[(4+(NT))*64 + lane];
    GSTEP(0, bL0)
    LOADW(1)
    GSTEP(1, bL1)
    LOADW(2)
    GSTEP(2, bL2)
    LOADW(3)
    GSTEP(3, bL3)
#undef GSTEP
#undef LOADW
    __syncthreads();  // [B3] all Z' reads done; region reusable

    if (L < 2){
      // step 4: write next Y = d * h (pk_mul) into [hidden][node] planes
      f32x4 d4s = *(const f32x4*)&lds_d[(w<<4) + (quad<<2)];
      f32x2 dA, dB; dA.x = d4s.x; dA.y = d4s.y; dB.x = d4s.z; dB.y = d4s.w;
      for (int nt = 0; nt < 4; ++nt){
        f32x2 u01, u23;
        u01.x = hcur[nt][0]; u01.y = hcur[nt][1];
        u23.x = hcur[nt][2]; u23.y = hcur[nt][3];
        u01 *= dA; u23 *= dB;                       /* pk_mul */
        unsigned h01, l01, h23, l23;
        split_pair2(u01, h01, l01);
        split_pair2(u23, h23, l23);
        *(uint2v*)(Yb + ybw + 2304*nt)        = uint2v{ h01, h23 };
        *(uint2v*)(Yb + ybw + 2304*nt + 9216) = uint2v{ l01, l23 };
      }
      __syncthreads();  // next layer's Y ready
    }
  }

  // ---------- head ----------
  unsigned* zbuf = (unsigned*)Yb + (w<<10);          // per-wave 4 KB pi-swizzle slice
  const int piL = (lane>>2) | ((lane&3)<<4);
  const int s0L = (piL>>2) & 1;

  // col-sum partials (quad-reduced in-wave) + server row
  {
    float cs[4];
    for (int nt = 0; nt < 4; ++nt){
      f32x2 sp, sq;
      sp.x = hcur[nt][0]; sp.y = hcur[nt][1];
      sq.x = hcur[nt][2]; sq.y = hcur[nt][3];
      sp += sq;                                     /* pk_add */
      float s = sp.x + sp.y;
      if (isSrv){ s -= hcur[nt][3]; lds_srv[c + (nt<<4)] = hcur[nt][3]; }
      s += __shfl_xor(s, 16);
      s += __shfl_xor(s, 32);
      cs[nt] = s;
    }
    if (quad == 0)
      for (int nt = 0; nt < 4; ++nt) lds_mp[(w<<6) + c + (nt<<4)] = cs[nt];
  }
  // transpose h -> A-frags via pi-swizzled per-wave slice
  for (int nt = 0; nt < 4; ++nt){
    int ks = nt >> 1;
    int lcBase = (quad<<2) + ((((nt&1)<<1) + (c>>3)) << 4);
    int e = c & 7;
    for (int r = 0; r < 4; ++r){
      unsigned pk = pack_hl(hcur[nt][r]);
      int lane_c = lcBase + r;
      int pi = (lane_c>>2) | ((lane_c&3)<<4);
      int sel = ((e>>2) ^ (pi>>2)) & 1;
      zbuf[(ks<<9) + (pi<<3) + (sel<<2) + (e&3)] = pk;
    }
  }
  __syncthreads();  // [Bh1] partials + srv + zbuf writes done; lds_d dead now

  // hoist epilogue constants (global, independent of the barriers)
  float wf2v[8];
#pragma unroll
  for (int nt = 0; nt < 8; ++nt) wf2v[nt] = Wf2[c + (nt<<4)];
  const float bb2 = bf2[0];

  // V = [mean(63 dev rows); srv] split to bf16 hi/lo (Vh aliases dead lds_d)
  if (t < 64){
    float mv = (lds_mp[t] + lds_mp[64+t] + lds_mp[128+t] + lds_mp[192+t]) * (1.0f/63.0f);
    unsigned short h,l; split2(mv,h,l);
    lds_Vh[t]=h; lds_Vl[t]=l;
  } else if (t < 128){
    float sv = lds_srv[t-64];
    unsigned short h,l; split2(sv,h,l);
    lds_Vh[t]=h; lds_Vl[t]=l;
  }
  __syncthreads();  // [Bh2] V ready; zbuf reads safe

  // read back h A-frags (issue all 4 LDS reads, then unpack)
  U4 hh0, hh1, hl0, hl1;
  {
    uint4v qa0 = *(const uint4v*)&zbuf[(0<<9) + (piL<<3) + (s0L<<2)];
    uint4v qb0 = *(const uint4v*)&zbuf[(0<<9) + (piL<<3) + ((1-s0L)<<2)];
    uint4v qa1 = *(const uint4v*)&zbuf[(1<<9) + (piL<<3) + (s0L<<2)];
    uint4v qb1 = *(const uint4v*)&zbuf[(1<<9) + (piL<<3) + ((1-s0L)<<2)];
    hh0.u = uint4v{ (qa0.y<<16)|(qa0.x&0xffffu), (qa0.w<<16)|(qa0.z&0xffffu),
                    (qb0.y<<16)|(qb0.x&0xffffu), (qb0.w<<16)|(qb0.z&0xffffu) };
    hl0.u = uint4v{ (qa0.y&0xffff0000u)|(qa0.x>>16), (qa0.w&0xffff0000u)|(qa0.z>>16),
                    (qb0.y&0xffff0000u)|(qb0.x>>16), (qb0.w&0xffff0000u)|(qb0.z>>16) };
    hh1.u = uint4v{ (qa1.y<<16)|(qa1.x&0xffffu), (qa1.w<<16)|(qa1.z&0xffffu),
                    (qb1.y<<16)|(qb1.x&0xffffu), (qb1.w<<16)|(qb1.z&0xffffu) };
    hl1.u = uint4v{ (qa1.y&0xffff0000u)|(qa1.x>>16), (qa1.w&0xffff0000u)|(qa1.z>>16),
                    (qb1.y&0xffff0000u)|(qb1.x>>16), (qb1.w&0xffff0000u)|(qb1.z>>16) };
  }

  // s1 = V @ Wfull + bf1 via MFMA (row 0 only); wave w owns cols 32w..32w+31
  {
    const uint4v* WfHp = (const uint4v*)(ws + WS_WF_H);
    const uint4v* WfLp = (const uint4v*)(ws + WS_WF_L);
    const int nt0 = (w<<1);
    float bf1a = 0.f, bf1b = 0.f;
    if (quad == 0){ bf1a = bf1[c + (w<<5)]; bf1b = bf1[c + (w<<5) + 16]; }
    f32x4 sacc0 = {0.f,0.f,0.f,0.f}, sacc1 = {0.f,0.f,0.f,0.f};
    for (int ks = 0; ks < 4; ++ks){
      U4 vh, vl;
      vh.u = *(const uint4v*)((const char*)lds_Vh + (ks<<6) + (quad<<4));
      vl.u = *(const uint4v*)((const char*)lds_Vl + (ks<<6) + (quad<<4));
      if (c != 0){ vh.u = uint4v{0,0,0,0}; vl.u = uint4v{0,0,0,0}; }
      U4 wh, wl;
      wh.u = WfHp[((ks<<3)+nt0)*64 + lane];
      wl.u = WfLp[((ks<<3)+nt0)*64 + lane];
      sacc0 = mfma16(vh, wh, sacc0);
      sacc0 = mfma16(vh, wl, sacc0);
      sacc0 = mfma16(vl, wh, sacc0);
      wh.u = WfHp[((ks<<3)+nt0+1)*64 + lane];
      wl.u = WfLp[((ks<<3)+nt0+1)*64 + lane];
      sacc1 = mfma16(vh, wh, sacc1);
      sacc1 = mfma16(vh, wl, sacc1);
      sacc1 = mfma16(vl, wh, sacc1);
    }
    if (quad == 0){
      int col0 = c + (w<<5);
      lds_s1[col0]      = sacc0[0] + bf1a;
      lds_s1[col0 + 16] = sacc1[0] + bf1b;
    }
  }
  __syncthreads();  // [Bh3] s1 ready

  // P = h @ Wa (3-pass split), single W buffer;
  // epilogue: out_n = sum_j relu(P+s1)[j]*Wf2[j]  (pk_add + pk_fma)
  const uint4v* WaHp = (const uint4v*)(ws + WS_WA_H);
  const uint4v* WaLp = (const uint4v*)(ws + WS_WA_L);
  float s1v[8];
#pragma unroll
  for (int nt = 0; nt < 8; ++nt) s1v[nt] = lds_s1[c + (nt<<4)];
  f32x2 oa01 = {0.f, 0.f}, oa23 = {0.f, 0.f};
#pragma unroll
  for (int nt = 0; nt < 8; ++nt){
    f32x4 g = {0.f,0.f,0.f,0.f};
    U4 wh, wl;
    wh.u = WaHp[nt*64 + lane];
    wl.u = WaLp[nt*64 + lane];
    g = mfma16(hh0, wh, g); g = mfma16(hh0, wl, g); g = mfma16(hl0, wh, g);
    wh.u = WaHp[(8+nt)*64 + lane];
    wl.u = WaLp[(8+nt)*64 + lane];
    g = mfma16(hh1, wh, g); g = mfma16(hh1, wl, g); g = mfma16(hl1, wh, g);
    f32x2 sv2; sv2.x = s1v[nt]; sv2.y = s1v[nt];
    f32x2 w22; w22.x = wf2v[nt]; w22.y = wf2v[nt];
    f32x2 g01, g23;
    g01.x = g[0]; g01.y = g[1]; g23.x = g[2]; g23.y = g[3];
    g01 += sv2; g23 += sv2;                         /* pk_add */
    g01.x = fmaxf(g01.x, 0.f); g01.y = fmaxf(g01.y, 0.f);
    g23.x = fmaxf(g23.x, 0.f); g23.y = fmaxf(g23.y, 0.f);
    oa01 += g01 * w22;                              /* pk_fma */
    oa23 += g23 * w22;                              /* pk_fma */
  }
  {
    float outacc[4] = {oa01.x, oa01.y, oa23.x, oa23.y};
#pragma unroll
    for (int r = 0; r < 4; ++r){
      float v = outacc[r];
      v += __shfl_xor(v, 1); v += __shfl_xor(v, 2);
      v += __shfl_xor(v, 4); v += __shfl_xor(v, 8);
      if (c == 0){
        int row = (w<<4) + (quad<<2) + r;
        if (row < 63) out[item*63 + row] = v + bb2;
      }
    }
  }
}

extern "C" void kernel_launch(void* const* d_in, const int* in_sizes, int n_in,
                              void* d_out, int out_size, void* d_ws, size_t ws_size,
                              hipStream_t stream)
{
  const float* dobs = (const float*)d_in[0];
  const float* sobs = (const float*)d_in[1];
  const float* adj  = (const float*)d_in[2];
  const float* Wdev = (const float*)d_in[3];
  const float* bdev = (const float*)d_in[4];
  const float* Wsrv = (const float*)d_in[5];
  const float* bsrv = (const float*)d_in[6];
  const float* W1   = (const float*)d_in[7];
  const float* b1   = (const float*)d_in[8];
  const float* W2   = (const float*)d_in[9];
  const float* b2   = (const float*)d_in[10];
  const float* W3   = (const float*)d_in[11];
  const float* b3   = (const float*)d_in[12];
  const float* Wf1  = (const float*)d_in[13];
  const float* bf1  = (const float*)d_in[14];
  const float* Wf2  = (const float*)d_in[15];
  const float* bf2  = (const float*)d_in[16];
  float* out = (float*)d_out;
  char* ws = (char*)d_ws;
  int nb = in_sizes[1] / 3;   // batch size (server_obs is B x 3)

  prep_weights<<<dim3(160), dim3(256), 0, stream>>>(Wdev, W1, W2, W3, Wf1, ws);
  pgcn_fused<<<dim3(nb), dim3(256), 0, stream>>>(dobs, sobs, adj, bdev, Wsrv, bsrv,
                                                 b1, b2, b3, bf1, Wf2, bf2, ws, out);
}

// Round 6
// 686.257 us; speedup vs baseline: 1.0110x; 1.0110x over previous
//
#include <hip/hip_runtime.h>
#include <hip/hip_bf16.h>
#include <stdint.h>

typedef __attribute__((ext_vector_type(8))) __bf16 bf16x8;
typedef __attribute__((ext_vector_type(4))) float f32x4;
typedef __attribute__((ext_vector_type(2))) float f32x2;
typedef __attribute__((ext_vector_type(4))) unsigned uint4v;
typedef __attribute__((ext_vector_type(2))) unsigned uint2v;

union U4 { uint4v u; bf16x8 b; };

// ---- d_ws layout (bytes) ----
#define WS_WDEV_H 0
#define WS_WDEV_L 4096
#define WS_W1_H   8192
#define WS_W1_L   16384
#define WS_W2_H   24576
#define WS_W2_L   32768
#define WS_W3_H   40960
#define WS_W3_L   49152
#define WS_WA_H   57344
#define WS_WA_L   73728
#define WS_WF_H   90112
#define WS_WF_L   122880
// total 155648 bytes

__device__ __forceinline__ unsigned short f2bf(float f){
  union { float f; unsigned u; } v; v.f = f;
  unsigned r = v.u + 0x7fffu + ((v.u >> 16) & 1u);
  return (unsigned short)(r >> 16);
}
__device__ __forceinline__ float bf2f(unsigned short h){
  union { unsigned u; float f; } v; v.u = ((unsigned)h) << 16; return v.f;
}
__device__ __forceinline__ void split2(float x, unsigned short& hi, unsigned short& lo){
  hi = f2bf(x);
  lo = f2bf(x - bf2f(hi));   // exact residual
}
__device__ __forceinline__ f32x4 mfma16(const U4& a, const U4& b, f32x4 c){
  return __builtin_amdgcn_mfma_f32_16x16x32_bf16(a.b, b.b, c, 0, 0, 0);
}

// ---- HW packed bf16 conversion (v_cvt_pk_bf16_f32, RNE — bit-identical to rnu) ----
__device__ __forceinline__ unsigned cvt_pk_bf(float a, float b){
  float2 p; p.x = a; p.y = b;
  union { __hip_bfloat162 h; unsigned u; } cv;
  cv.h = __float22bfloat162_rn(p);          // low16 = bf(a), high16 = bf(b)
  return cv.u;
}
// hi2 = (bf16(x1)<<16)|bf16(x0), lo2 = same for RN residuals (scalar form, R10)
__device__ __forceinline__ void split_pair(float x0, float x1, unsigned& hi2, unsigned& lo2){
  hi2 = cvt_pk_bf(x0, x1);
  lo2 = cvt_pk_bf(x0 - __uint_as_float(hi2 << 16),
                  x1 - __uint_as_float(hi2 & 0xffff0000u));
}
// R12: packed-residual variant (v_pk_add_f32 for the residual sub) — used ONLY
// in low-register-pressure regions (step2/step4). Bit-identical IEEE ops.
__device__ __forceinline__ void split_pair2(f32x2 xy, unsigned& hi2, unsigned& lo2){
  hi2 = cvt_pk_bf(xy.x, xy.y);
  f32x2 b;
  b.x = __uint_as_float(hi2 << 16);
  b.y = __uint_as_float(hi2 & 0xffff0000u);
  f32x2 r = xy - b;                         // packed sub
  lo2 = cvt_pk_bf(r.x, r.y);
}
// v_perm_b32 byte-selectors: build (lo16<<16)|hi16 words from split_pair output.
// perm(S0,S1,sel): sel byte 0..3 -> S1 bytes, 4..7 -> S0 bytes.
#define SEL_LOHALF 0x05040100u   // (S0.low16 << 16) | S1.low16
#define SEL_HIHALF 0x07060302u   // (S0.hi16  << 16) | S1.hi16

// ------------------------------------------------------------------
// prep kernel: weights -> hi/lo bf16 MFMA B-fragments.
// B-frag: idx = ((ks*NT+nt)*64 + lane)*8 + j ; k = ks*32+(lane>>4)*8+j, n = nt*16+(lane&15)
// ------------------------------------------------------------------
extern "C" __global__ void prep_weights(const float* __restrict__ Wdev,
                                        const float* __restrict__ W1,
                                        const float* __restrict__ W2,
                                        const float* __restrict__ W3,
                                        const float* __restrict__ Wf1,
                                        char* __restrict__ ws)
{
  unsigned short* WdevH = (unsigned short*)(ws + WS_WDEV_H);
  unsigned short* WdevL = (unsigned short*)(ws + WS_WDEV_L);
  unsigned short* WH[3] = {(unsigned short*)(ws+WS_W1_H),(unsigned short*)(ws+WS_W2_H),(unsigned short*)(ws+WS_W3_H)};
  unsigned short* WL[3] = {(unsigned short*)(ws+WS_W1_L),(unsigned short*)(ws+WS_W2_L),(unsigned short*)(ws+WS_W3_L)};
  unsigned short* WaH = (unsigned short*)(ws + WS_WA_H);
  unsigned short* WaL = (unsigned short*)(ws + WS_WA_L);
  unsigned short* WfH = (unsigned short*)(ws + WS_WF_H);
  unsigned short* WfL = (unsigned short*)(ws + WS_WF_L);
  const int total = 2048 + 3*4096 + 8192 + 16384;
  for (int idx = blockIdx.x*256 + threadIdx.x; idx < total; idx += gridDim.x*256){
    if (idx < 2048){                       // Wdev (14x64), K padded to 32, NT=4
      int tt = idx;
      int frag = tt >> 9, within = tt & 511, lane = within >> 3, j = within & 7;
      int nt = frag & 3;
      int k = ((lane>>4)<<3) + j;
      int n = (nt<<4) + (lane & 15);
      float v = (k < 14) ? Wdev[k*64 + n] : 0.f;
      unsigned short h,l; split2(v,h,l); WdevH[tt]=h; WdevL[tt]=l;
    } else if (idx < 2048 + 3*4096){       // W1/W2/W3 (64x64), KS=2, NT=4
      int tt = idx - 2048; int Li = tt / 4096; int r = tt - Li*4096;
      int frag = r >> 9, within = r & 511, lane = within >> 3, j = within & 7;
      int ks = frag >> 2, nt = frag & 3;
      int k = (ks<<5) + ((lane>>4)<<3) + j;
      int n = (nt<<4) + (lane & 15);
      const float* W = (Li==0) ? W1 : ((Li==1) ? W2 : W3);
      float v = W[k*64 + n];
      unsigned short h,l; split2(v,h,l); WH[Li][r]=h; WL[Li][r]=l;
    } else if (idx < 2048 + 3*4096 + 8192){ // Wa = Wf1 rows 0..63 (64x128), KS=2, NT=8
      int r = idx - (2048 + 3*4096);
      int frag = r >> 9, within = r & 511, lane = within >> 3, j = within & 7;
      int ks = frag >> 3, nt = frag & 7;
      int k = (ks<<5) + ((lane>>4)<<3) + j;
      int n = (nt<<4) + (lane & 15);
      float v = Wf1[k*128 + n];
      unsigned short h,l; split2(v,h,l); WaH[r]=h; WaL[r]=l;
    } else {                                // Wfull = Wf1 rows 64..191 (128x128), KS=4, NT=8
      int r = idx - (2048 + 3*4096 + 8192);
      int frag = r >> 9, within = r & 511, lane = within >> 3, j = within & 7;
      int ks = frag >> 3, nt = frag & 7;
      int k = (ks<<5) + ((lane>>4)<<3) + j;
      int n = (nt<<4) + (lane & 15);
      float v = Wf1[(64 + k)*128 + n];
      unsigned short h,l; split2(v,h,l); WfH[r]=h; WfL[r]=l;
    }
  }
}

// ------------------------------------------------------------------
// fused PGCN critic. R10 structure (best, 346us, no spills) + R12:
//   - packed f32x2 math ONLY in step2/step4/head-epilogue (short-lived
//     temps after the step-1 register peak). R11's blanket packing spilled
//     (WRITE_SIZE 4.5MB -> 201MB); embed/A-frag/GSTEP stay scalar.
//   - v_perm_b32 for all 16-bit repacking (head transpose + readback):
//     bit-exact byte shuffles replace shift/and/or + 2nd cvt_pk chains.
// ------------------------------------------------------------------
extern "C" __global__ __launch_bounds__(256, 6)
void pgcn_fused(const float* __restrict__ dobs, const float* __restrict__ sobs,
                const float* __restrict__ adj,
                const float* __restrict__ bdev,
                const float* __restrict__ Wsrv, const float* __restrict__ bsrv,
                const float* __restrict__ b1, const float* __restrict__ b2,
                const float* __restrict__ b3,
                const float* __restrict__ bf1, const float* __restrict__ Wf2,
                const float* __restrict__ bf2,
                const char* __restrict__ ws, float* __restrict__ out)
{
  // hi plane: halfwords [0, 4608)  (64 rows x 72), lo plane: [4608, 9216); 18432 B
  __shared__ __align__(16) unsigned short     lds_Yr[9216];
  __shared__ __align__(16) unsigned long long lds_Abits[64];   // LIVE all layers
  __shared__ __align__(16) float    lds_d[64];                  // dead by head
  // ---- head-phase aliases (live only after the last GCN barrier) ----
  char* Yb = (char*)lds_Yr;
  float*          lds_mp  = (float*)(Yb + 16384);               // 1024 B
  float*          lds_srv = (float*)(Yb + 17408);               //  256 B
  float*          lds_s1  = (float*)(Yb + 17664);               //  512 B
  unsigned short* lds_Vl  = (unsigned short*)(Yb + 18176);      //  256 B
  unsigned short* lds_Vh  = (unsigned short*)lds_d;             //  256 B

  const int t = threadIdx.x;
  const int w = t >> 6;
  const int lane = t & 63;
  const int quad = lane >> 4;
  const int c = lane & 15;
  const long item = blockIdx.x;
  const bool isSrv = (w == 3) && (quad == 3);

  // ---------- stage adjacency as bitmask ----------
  {
    const f32x4* src = (const f32x4*)(adj + item*4096 + ((t>>2)<<6) + ((t&3)<<4));
    unsigned bits = 0;
    for (int i = 0; i < 4; ++i){
      f32x4 v = src[i];
      unsigned b = (v.x != 0.f) | (((unsigned)(v.y != 0.f))<<1)
                 | (((unsigned)(v.z != 0.f))<<2) | (((unsigned)(v.w != 0.f))<<3);
      bits |= b << (i<<2);
    }
    ((unsigned short*)lds_Abits)[t] = (unsigned short)bits;
  }

  // ---------- load device_obs rows as A-operand frags (hi/lo) ----------
  unsigned ahi[4] = {0,0,0,0}, alo[4] = {0,0,0,0};
  {
    int m = (w<<4) + c;
    if (quad < 2 && m < 63){
      const float* rp = dobs + item*882 + m*14 + (quad<<3);
      float e[8];
      f32x2 p0 = *(const f32x2*)(rp);
      f32x2 p1 = *(const f32x2*)(rp+2);
      f32x2 p2 = *(const f32x2*)(rp+4);
      e[0]=p0.x; e[1]=p0.y; e[2]=p1.x; e[3]=p1.y; e[4]=p2.x; e[5]=p2.y;
      if (quad == 0){
        f32x2 p3 = *(const f32x2*)(rp+6);
        e[6]=p3.x; e[7]=p3.y;
      } else {
        e[6]=0.f; e[7]=0.f;                   // k = 14,15 pad
      }
      for (int d0 = 0; d0 < 4; ++d0)
        split_pair(e[2*d0], e[2*d0+1], ahi[d0], alo[d0]);
    }
  }

  // ---------- early hoisted per-thread constants ----------
  float bdv0 = bdev[c], bdv1 = bdev[c+16], bdv2 = bdev[c+32], bdv3 = bdev[c+48];
  float srvv4[4];
  if (isSrv){
    float s0 = sobs[item*3+0], s1a = sobs[item*3+1], s2a = sobs[item*3+2];
#pragma unroll
    for (int nt = 0; nt < 4; ++nt){
      int col = c + (nt<<4);
      float v = s0*Wsrv[col] + s1a*Wsrv[64+col] + s2a*Wsrv[128+col] + bsrv[col];
      srvv4[nt] = fmaxf(v, 0.f);
    }
  }
  __syncthreads();   // [S1] bits ready

  // ---------- degrees from popcount ----------
  if (t < 64){
    unsigned long long mk = lds_Abits[t];
    int deg = __popcll(mk);
    lds_d[t] = 1.0f / sqrtf((float)(deg < 1 ? 1 : deg));
  }
  __syncthreads();   // [S2] d ready

  // LDS base offsets (bytes)
  const int ybw = (c*72 + (w<<4) + (quad<<2)) << 1;          // Y write (+2304*nt)
  const int yrd = (c*72 + (quad<<3)) << 1;                    // Y read  (+2304*mt+64*ks)
  const int zbw = (((w<<4)+c)*72 + (quad<<2)) << 1;           // Z write (+32*mt)
  const int zrd = (((w<<4)+c)*72 + (quad<<3)) << 1;           // Z read  (+64*ks)

  float hcur[4][4];

  // ---------- embed: x = relu(dobs@Wdev + bdev); row63 = server; write Y1 = d*x
  {
    f32x4 dE = *(const f32x4*)&lds_d[(w<<4) + (quad<<2)];
    U4 a_h, a_l;
    a_h.u = uint4v{ahi[0],ahi[1],ahi[2],ahi[3]};
    a_l.u = uint4v{alo[0],alo[1],alo[2],alo[3]};
    const uint4v* WdHp = (const uint4v*)(ws + WS_WDEV_H);
    const uint4v* WdLp = (const uint4v*)(ws + WS_WDEV_L);
#define EMB(NT, BB) { \
    U4 wh, wl; \
    wh.u = WdHp[(NT)*64 + lane]; wl.u = WdLp[(NT)*64 + lane]; \
    f32x4 g = {0.f,0.f,0.f,0.f}; \
    g = mfma16(a_h, wh, g); \
    g = mfma16(a_h, wl, g); \
    g = mfma16(a_l, wh, g); \
    float y0 = fmaxf(g[0] + (BB), 0.f); \
    float y1 = fmaxf(g[1] + (BB), 0.f); \
    float y2 = fmaxf(g[2] + (BB), 0.f); \
    float y3 = fmaxf(g[3] + (BB), 0.f); \
    if (isSrv) y3 = srvv4[NT];            /* node 63 = server embedding */ \
    y0 *= dE.x; y1 *= dE.y; y2 *= dE.z; y3 *= dE.w;       /* Y = d * x */ \
    unsigned h01,l01,h23,l23; \
    split_pair(y0, y1, h01, l01); \
    split_pair(y2, y3, h23, l23); \
    *(uint2v*)(Yb + ybw + 2304*(NT))        = uint2v{ h01, h23 }; \
    *(uint2v*)(Yb + ybw + 2304*(NT) + 9216) = uint2v{ l01, l23 }; }
    EMB(0, bdv0)
    EMB(1, bdv1)
    EMB(2, bdv2)
    EMB(3, bdv3)
#undef EMB
  }
  __syncthreads();   // Y1 ready

  // ---------- 3 GCN layers ----------
  const uint4v* WH_tab[3] = {(const uint4v*)(ws+WS_W1_H),(const uint4v*)(ws+WS_W2_H),(const uint4v*)(ws+WS_W3_H)};
  const uint4v* WL_tab[3] = {(const uint4v*)(ws+WS_W1_L),(const uint4v*)(ws+WS_W2_L),(const uint4v*)(ws+WS_W3_L)};
  const float* bias_tab[3] = {b1, b2, b3};

  for (int L = 0; L < 3; ++L){
    const uint4v* WHp = WH_tab[L];
    const uint4v* WLp = WL_tab[L];
    const float* bp = bias_tab[L];
    float bL0 = bp[c], bL1 = bp[c+16], bL2 = bp[c+32], bL3 = bp[c+48];
    float ddc = lds_d[(w<<4) + c];

    // atk re-derived per layer from LIVE Abits — live range = step1 only
    U4 atk0, atk1;
    {
      unsigned long long mk = lds_Abits[(w<<4) + c];
      unsigned by0 = (unsigned)(mk >> (quad<<3)) & 0xffu;
      unsigned by1 = (unsigned)(mk >> (32 + (quad<<3))) & 0xffu;
#pragma unroll
      for (int r = 0; r < 4; ++r){
        unsigned e0 = 0u - ((by0 >> (2*r)) & 1u);
        unsigned o0 = 0u - ((by0 >> (2*r+1)) & 1u);
        atk0.u[r] = (e0 & 0x3f80u) | (o0 & 0x3f800000u);
        unsigned e1 = 0u - ((by1 >> (2*r)) & 1u);
        unsigned o1 = 0u - ((by1 >> (2*r+1)) & 1u);
        atk1.u[r] = (e1 & 0x3f80u) | (o1 & 0x3f800000u);
      }
    }

    // step 1 (swapped): Zt = Yt @ At, depth-2 pipeline over mt (LDS reads only)
    f32x4 zacc0, zacc1, zacc2, zacc3;
    {
      U4 yAh0,yAl0,yAh1,yAl1, yBh0,yBl0,yBh1,yBl1;
#define LOADY(H0,L0,H1,L1, MT) \
      H0.u = *(const uint4v*)(Yb + yrd + 2304*(MT)); \
      L0.u = *(const uint4v*)(Yb + yrd + 2304*(MT) + 9216); \
      H1.u = *(const uint4v*)(Yb + yrd + 2304*(MT) + 64); \
      L1.u = *(const uint4v*)(Yb + yrd + 2304*(MT) + 64 + 9216);
#define ZSTEP(ZD, H0,L0,H1,L1) { \
      f32x4 g = {0.f,0.f,0.f,0.f}; \
      g = mfma16(H0, atk0, g); \
      g = mfma16(L0, atk0, g); \
      g = mfma16(H1, atk1, g); \
      g = mfma16(L1, atk1, g); \
      ZD = g; }
      LOADY(yAh0,yAl0,yAh1,yAl1, 0)
      LOADY(yBh0,yBl0,yBh1,yBl1, 1)
      ZSTEP(zacc0, yAh0,yAl0,yAh1,yAl1)
      LOADY(yAh0,yAl0,yAh1,yAl1, 2)
      ZSTEP(zacc1, yBh0,yBl0,yBh1,yBl1)
      LOADY(yBh0,yBl0,yBh1,yBl1, 3)
      ZSTEP(zacc2, yAh0,yAl0,yAh1,yAl1)
      ZSTEP(zacc3, yBh0,yBl0,yBh1,yBl1)
#undef LOADY
#undef ZSTEP
    }
    __syncthreads();  // [B2] all Y reads done; region reusable

    // prefetch step-3 weights nt=0 NOW: L2 latency hides under step-2 LDS work
    U4 w0h, w0l, w1h, w1l;
    w0h.u = WHp[0*64 + lane];
    w0l.u = WLp[0*64 + lane];
    w1h.u = WHp[4*64 + lane];
    w1l.u = WLp[4*64 + lane];

    // step 2: Z' = d*Zt (pk_mul + packed-residual split), regroup into rows
    {
      f32x2 dd2; dd2.x = ddc; dd2.y = ddc;
#define Z2(ZA, OFF) { \
      f32x2 p01, p23; \
      p01.x = ZA[0]; p01.y = ZA[1]; p23.x = ZA[2]; p23.y = ZA[3]; \
      p01 *= dd2; p23 *= dd2;                       /* pk_mul */ \
      unsigned h01,l01,h23,l23; \
      split_pair2(p01, h01, l01); \
      split_pair2(p23, h23, l23); \
      *(uint2v*)(Yb + zbw + (OFF))        = uint2v{ h01, h23 }; \
      *(uint2v*)(Yb + zbw + (OFF) + 9216) = uint2v{ l01, l23 }; }
      Z2(zacc0,  0)
      Z2(zacc1, 32)
      Z2(zacc2, 64)
      Z2(zacc3, 96)
#undef Z2
    }
    // wave-private rows: order LDS writes before reads WITHOUT draining vmcnt
    asm volatile("s_waitcnt lgkmcnt(0)" ::: "memory");
    U4 zh0, zl0, zh1, zl1;
    zh0.u = *(const uint4v*)(Yb + zrd);
    zl0.u = *(const uint4v*)(Yb + zrd + 9216);
    zh1.u = *(const uint4v*)(Yb + zrd + 64);
    zl1.u = *(const uint4v*)(Yb + zrd + 64 + 9216);

    // step 3: G = Z' @ W (3-pass split), h = relu(G + b); single W buffer
#define GSTEP(NT, BB) { \
    f32x4 g = {0.f,0.f,0.f,0.f}; \
    g = mfma16(zh0, w0h, g); g = mfma16(zh0, w0l, g); g = mfma16(zl0, w0h, g); \
    g = mfma16(zh1, w1h, g); g = mfma16(zh1, w1l, g); g = mfma16(zl1, w1h, g); \
    hcur[NT][0] = fmaxf(g[0] + (BB), 0.f); \
    hcur[NT][1] = fmaxf(g[1] + (BB), 0.f); \
    hcur[NT][2] = fmaxf(g[2] + (BB), 0.f); \
    hcur[NT][3] = fmaxf(g[3] + (BB), 0.f); }
#define LOADW(NT) \
    w0h.u = WHp[(NT)*64 + lane]; \
    w0l.u = WLp[(NT)*64 + lane]; \
    w1h.u = WHp[(4+(NT))*64 + lane]; \
    w1l.u = WLp[(4+(NT))*64 + lane];
    GSTEP(0, bL0)
    LOADW(1)
    GSTEP(1, bL1)
    LOADW(2)
    GSTEP(2, bL2)
    LOADW(3)
    GSTEP(3, bL3)
#undef GSTEP
#undef LOADW
    __syncthreads();  // [B3] all Z' reads done; region reusable

    if (L < 2){
      // step 4: write next Y = d * h (pk_mul + packed split) into planes
      f32x4 d4s = *(const f32x4*)&lds_d[(w<<4) + (quad<<2)];
      f32x2 dA, dB; dA.x = d4s.x; dA.y = d4s.y; dB.x = d4s.z; dB.y = d4s.w;
      for (int nt = 0; nt < 4; ++nt){
        f32x2 u01, u23;
        u01.x = hcur[nt][0]; u01.y = hcur[nt][1];
        u23.x = hcur[nt][2]; u23.y = hcur[nt][3];
        u01 *= dA; u23 *= dB;                       /* pk_mul */
        unsigned h01, l01, h23, l23;
        split_pair2(u01, h01, l01);
        split_pair2(u23, h23, l23);
        *(uint2v*)(Yb + ybw + 2304*nt)        = uint2v{ h01, h23 };
        *(uint2v*)(Yb + ybw + 2304*nt + 9216) = uint2v{ l01, l23 };
      }
      __syncthreads();  // next layer's Y ready
    }
  }

  // ---------- head ----------
  unsigned* zbuf = (unsigned*)Yb + (w<<10);          // per-wave 4 KB pi-swizzle slice
  const int piL = (lane>>2) | ((lane&3)<<4);
  const int s0L = (piL>>2) & 1;

  // col-sum partials (quad-reduced in-wave) + server row
  {
    float cs[4];
    for (int nt = 0; nt < 4; ++nt){
      float s = hcur[nt][0] + hcur[nt][1] + hcur[nt][2] + hcur[nt][3];
      if (isSrv){ s -= hcur[nt][3]; lds_srv[c + (nt<<4)] = hcur[nt][3]; }
      s += __shfl_xor(s, 16);
      s += __shfl_xor(s, 32);
      cs[nt] = s;
    }
    if (quad == 0)
      for (int nt = 0; nt < 4; ++nt) lds_mp[(w<<6) + c + (nt<<4)] = cs[nt];
  }
  // transpose h -> A-frags via pi-swizzled per-wave slice.
  // R12: split two values at once (split_pair) then v_perm into the
  // (lo16<<16)|hi16 zbuf element format — bit-identical, ~half the VALU.
  for (int nt = 0; nt < 4; ++nt){
    int ks = nt >> 1;
    int lcBase = (quad<<2) + ((((nt&1)<<1) + (c>>3)) << 4);
    int e = c & 7;
    unsigned pk0, pk1, pk2, pk3;
    {
      unsigned h2, l2;
      split_pair(hcur[nt][0], hcur[nt][1], h2, l2);
      pk0 = __builtin_amdgcn_perm(l2, h2, SEL_LOHALF);
      pk1 = __builtin_amdgcn_perm(l2, h2, SEL_HIHALF);
      split_pair(hcur[nt][2], hcur[nt][3], h2, l2);
      pk2 = __builtin_amdgcn_perm(l2, h2, SEL_LOHALF);
      pk3 = __builtin_amdgcn_perm(l2, h2, SEL_HIHALF);
    }
    unsigned pk[4] = {pk0, pk1, pk2, pk3};
#pragma unroll
    for (int r = 0; r < 4; ++r){
      int lane_c = lcBase + r;
      int pi = (lane_c>>2) | ((lane_c&3)<<4);
      int sel = ((e>>2) ^ (pi>>2)) & 1;
      zbuf[(ks<<9) + (pi<<3) + (sel<<2) + (e&3)] = pk[r];
    }
  }
  __syncthreads();  // [Bh1] partials + srv + zbuf writes done; lds_d dead now

  // hoist epilogue constants (global, independent of the barriers)
  float wf2v[8];
#pragma unroll
  for (int nt = 0; nt < 8; ++nt) wf2v[nt] = Wf2[c + (nt<<4)];
  const float bb2 = bf2[0];

  // V = [mean(63 dev rows); srv] split to bf16 hi/lo (Vh aliases dead lds_d)
  if (t < 64){
    float mv = (lds_mp[t] + lds_mp[64+t] + lds_mp[128+t] + lds_mp[192+t]) * (1.0f/63.0f);
    unsigned short h,l; split2(mv,h,l);
    lds_Vh[t]=h; lds_Vl[t]=l;
  } else if (t < 128){
    float sv = lds_srv[t-64];
    unsigned short h,l; split2(sv,h,l);
    lds_Vh[t]=h; lds_Vl[t]=l;
  }
  __syncthreads();  // [Bh2] V ready; zbuf reads safe

  // read back h A-frags — v_perm repack (bit-identical to shift/and/or)
  U4 hh0, hh1, hl0, hl1;
  {
    uint4v qa0 = *(const uint4v*)&zbuf[(0<<9) + (piL<<3) + (s0L<<2)];
    uint4v qb0 = *(const uint4v*)&zbuf[(0<<9) + (piL<<3) + ((1-s0L)<<2)];
    uint4v qa1 = *(const uint4v*)&zbuf[(1<<9) + (piL<<3) + (s0L<<2)];
    uint4v qb1 = *(const uint4v*)&zbuf[(1<<9) + (piL<<3) + ((1-s0L)<<2)];
    hh0.u = uint4v{ __builtin_amdgcn_perm(qa0.y, qa0.x, SEL_LOHALF),
                    __builtin_amdgcn_perm(qa0.w, qa0.z, SEL_LOHALF),
                    __builtin_amdgcn_perm(qb0.y, qb0.x, SEL_LOHALF),
                    __builtin_amdgcn_perm(qb0.w, qb0.z, SEL_LOHALF) };
    hl0.u = uint4v{ __builtin_amdgcn_perm(qa0.y, qa0.x, SEL_HIHALF),
                    __builtin_amdgcn_perm(qa0.w, qa0.z, SEL_HIHALF),
                    __builtin_amdgcn_perm(qb0.y, qb0.x, SEL_HIHALF),
                    __builtin_amdgcn_perm(qb0.w, qb0.z, SEL_HIHALF) };
    hh1.u = uint4v{ __builtin_amdgcn_perm(qa1.y, qa1.x, SEL_LOHALF),
                    __builtin_amdgcn_perm(qa1.w, qa1.z, SEL_LOHALF),
                    __builtin_amdgcn_perm(qb1.y, qb1.x, SEL_LOHALF),
                    __builtin_amdgcn_perm(qb1.w, qb1.z, SEL_LOHALF) };
    hl1.u = uint4v{ __builtin_amdgcn_perm(qa1.y, qa1.x, SEL_HIHALF),
                    __builtin_amdgcn_perm(qa1.w, qa1.z, SEL_HIHALF),
                    __builtin_amdgcn_perm(qb1.y, qb1.x, SEL_HIHALF),
                    __builtin_amdgcn_perm(qb1.w, qb1.z, SEL_HIHALF) };
  }

  // s1 = V @ Wfull + bf1 via MFMA (row 0 only); wave w owns cols 32w..32w+31
  {
    const uint4v* WfHp = (const uint4v*)(ws + WS_WF_H);
    const uint4v* WfLp = (const uint4v*)(ws + WS_WF_L);
    const int nt0 = (w<<1);
    float bf1a = 0.f, bf1b = 0.f;
    if (quad == 0){ bf1a = bf1[c + (w<<5)]; bf1b = bf1[c + (w<<5) + 16]; }
    f32x4 sacc0 = {0.f,0.f,0.f,0.f}, sacc1 = {0.f,0.f,0.f,0.f};
    for (int ks = 0; ks < 4; ++ks){
      U4 vh, vl;
      vh.u = *(const uint4v*)((const char*)lds_Vh + (ks<<6) + (quad<<4));
      vl.u = *(const uint4v*)((const char*)lds_Vl + (ks<<6) + (quad<<4));
      if (c != 0){ vh.u = uint4v{0,0,0,0}; vl.u = uint4v{0,0,0,0}; }
      U4 wh, wl;
      wh.u = WfHp[((ks<<3)+nt0)*64 + lane];
      wl.u = WfLp[((ks<<3)+nt0)*64 + lane];
      sacc0 = mfma16(vh, wh, sacc0);
      sacc0 = mfma16(vh, wl, sacc0);
      sacc0 = mfma16(vl, wh, sacc0);
      wh.u = WfHp[((ks<<3)+nt0+1)*64 + lane];
      wl.u = WfLp[((ks<<3)+nt0+1)*64 + lane];
      sacc1 = mfma16(vh, wh, sacc1);
      sacc1 = mfma16(vh, wl, sacc1);
      sacc1 = mfma16(vl, wh, sacc1);
    }
    if (quad == 0){
      int col0 = c + (w<<5);
      lds_s1[col0]      = sacc0[0] + bf1a;
      lds_s1[col0 + 16] = sacc1[0] + bf1b;
    }
  }
  __syncthreads();  // [Bh3] s1 ready

  // P = h @ Wa (3-pass split), single W buffer;
  // epilogue: out_n = sum_j relu(P+s1)[j]*Wf2[j]  (packed add/fma)
  const uint4v* WaHp = (const uint4v*)(ws + WS_WA_H);
  const uint4v* WaLp = (const uint4v*)(ws + WS_WA_L);
  float s1v[8];
#pragma unroll
  for (int nt = 0; nt < 8; ++nt) s1v[nt] = lds_s1[c + (nt<<4)];
  f32x2 oa01 = {0.f, 0.f}, oa23 = {0.f, 0.f};
#pragma unroll
  for (int nt = 0; nt < 8; ++nt){
    f32x4 g = {0.f,0.f,0.f,0.f};
    U4 wh, wl;
    wh.u = WaHp[nt*64 + lane];
    wl.u = WaLp[nt*64 + lane];
    g = mfma16(hh0, wh, g); g = mfma16(hh0, wl, g); g = mfma16(hl0, wh, g);
    wh.u = WaHp[(8+nt)*64 + lane];
    wl.u = WaLp[(8+nt)*64 + lane];
    g = mfma16(hh1, wh, g); g = mfma16(hh1, wl, g); g = mfma16(hl1, wh, g);
    f32x2 sv2; sv2.x = s1v[nt]; sv2.y = s1v[nt];
    f32x2 w22; w22.x = wf2v[nt]; w22.y = wf2v[nt];
    f32x2 g01, g23;
    g01.x = g[0]; g01.y = g[1]; g23.x = g[2]; g23.y = g[3];
    g01 += sv2; g23 += sv2;                         /* pk_add */
    g01.x = fmaxf(g01.x, 0.f); g01.y = fmaxf(g01.y, 0.f);
    g23.x = fmaxf(g23.x, 0.f); g23.y = fmaxf(g23.y, 0.f);
    oa01 += g01 * w22;                              /* pk_fma */
    oa23 += g23 * w22;                              /* pk_fma */
  }
  {
    float outacc[4] = {oa01.x, oa01.y, oa23.x, oa23.y};
#pragma unroll
    for (int r = 0; r < 4; ++r){
      float v = outacc[r];
      v += __shfl_xor(v, 1); v += __shfl_xor(v, 2);
      v += __shfl_xor(v, 4); v += __shfl_xor(v, 8);
      if (c == 0){
        int row = (w<<4) + (quad<<2) + r;
        if (row < 63) out[item*63 + row] = v + bb2;
      }
    }
  }
}

extern "C" void kernel_launch(void* const* d_in, const int* in_sizes, int n_in,
                              void* d_out, int out_size, void* d_ws, size_t ws_size,
                              hipStream_t stream)
{
  const float* dobs = (const float*)d_in[0];
  const float* sobs = (const float*)d_in[1];
  const float* adj  = (const float*)d_in[2];
  const float* Wdev = (const float*)d_in[3];
  const float* bdev = (const float*)d_in[4];
  const float* Wsrv = (const float*)d_in[5];
  const float* bsrv = (const float*)d_in[6];
  const float* W1   = (const float*)d_in[7];
  const float* b1   = (const float*)d_in[8];
  const float* W2   = (const float*)d_in[9];
  const float* b2   = (const float*)d_in[10];
  const float* W3   = (const float*)d_in[11];
  const float* b3   = (const float*)d_in[12];
  const float* Wf1  = (const float*)d_in[13];
  const float* bf1  = (const float*)d_in[14];
  const float* Wf2  = (const float*)d_in[15];
  const float* bf2  = (const float*)d_in[16];
  float* out = (float*)d_out;
  char* ws = (char*)d_ws;
  int nb = in_sizes[1] / 3;   // batch size (server_obs is B x 3)

  prep_weights<<<dim3(160), dim3(256), 0, stream>>>(Wdev, W1, W2, W3, Wf1, ws);
  pgcn_fused<<<dim3(nb), dim3(256), 0, stream>>>(dobs, sobs, adj, bdev, Wsrv, bsrv,
                                                 b1, b2, b3, bf1, Wf2, bf2, ws, out);
}

// Round 7
// 627.240 us; speedup vs baseline: 1.1061x; 1.0941x over previous
//
#include <hip/hip_runtime.h>
#include <hip/hip_bf16.h>
#include <stdint.h>

typedef __attribute__((ext_vector_type(8))) __bf16 bf16x8;
typedef __attribute__((ext_vector_type(4))) float f32x4;
typedef __attribute__((ext_vector_type(2))) float f32x2;
typedef __attribute__((ext_vector_type(4))) unsigned uint4v;
typedef __attribute__((ext_vector_type(2))) unsigned uint2v;

union U4 { uint4v u; bf16x8 b; };

// ---- d_ws layout (bytes) ----
#define WS_WDEV_H 0
#define WS_WDEV_L 4096
#define WS_W1_H   8192
#define WS_W1_L   16384
#define WS_W2_H   24576
#define WS_W2_L   32768
#define WS_W3_H   40960
#define WS_W3_L   49152
#define WS_WA_H   57344
#define WS_WA_L   73728
#define WS_WF_H   90112
#define WS_WF_L   122880
// total 155648 bytes

__device__ __forceinline__ unsigned short f2bf(float f){
  union { float f; unsigned u; } v; v.f = f;
  unsigned r = v.u + 0x7fffu + ((v.u >> 16) & 1u);
  return (unsigned short)(r >> 16);
}
__device__ __forceinline__ float bf2f(unsigned short h){
  union { unsigned u; float f; } v; v.u = ((unsigned)h) << 16; return v.f;
}
__device__ __forceinline__ void split2(float x, unsigned short& hi, unsigned short& lo){
  hi = f2bf(x);
  lo = f2bf(x - bf2f(hi));   // exact residual
}
__device__ __forceinline__ f32x4 mfma16(const U4& a, const U4& b, f32x4 c){
  return __builtin_amdgcn_mfma_f32_16x16x32_bf16(a.b, b.b, c, 0, 0, 0);
}

// R13: wave-priority hints around MFMA clusters (zero register cost).
// Mechanism: ~6 independent blocks/CU at different phases; boost MFMA-phase
// waves over other blocks' VALU/staging waves (m191 attn regime, +4-7%).
#define PRIO1 __builtin_amdgcn_s_setprio(1)
#define PRIO0 __builtin_amdgcn_s_setprio(0)

// ---- HW packed bf16 conversion (v_cvt_pk_bf16_f32, RNE — bit-identical to rnu) ----
__device__ __forceinline__ unsigned cvt_pk_bf(float a, float b){
  float2 p; p.x = a; p.y = b;
  union { __hip_bfloat162 h; unsigned u; } cv;
  cv.h = __float22bfloat162_rn(p);          // low16 = bf(a), high16 = bf(b)
  return cv.u;
}
// hi2 = (bf16(x1)<<16)|bf16(x0), lo2 = same for RN residuals
__device__ __forceinline__ void split_pair(float x0, float x1, unsigned& hi2, unsigned& lo2){
  hi2 = cvt_pk_bf(x0, x1);
  lo2 = cvt_pk_bf(x0 - __uint_as_float(hi2 << 16),
                  x1 - __uint_as_float(hi2 & 0xffff0000u));
}
// (lo16<<16)|hi16 for one value (head zbuf element format)
__device__ __forceinline__ unsigned pack_hl(float z){
  unsigned h = cvt_pk_bf(z, 0.f) & 0xffffu;
  float r = z - __uint_as_float(h << 16);
  return (cvt_pk_bf(0.f, r) & 0xffff0000u) | h;
}

// ------------------------------------------------------------------
// prep kernel: weights -> hi/lo bf16 MFMA B-fragments.
// B-frag: idx = ((ks*NT+nt)*64 + lane)*8 + j ; k = ks*32+(lane>>4)*8+j, n = nt*16+(lane&15)
// ------------------------------------------------------------------
extern "C" __global__ void prep_weights(const float* __restrict__ Wdev,
                                        const float* __restrict__ W1,
                                        const float* __restrict__ W2,
                                        const float* __restrict__ W3,
                                        const float* __restrict__ Wf1,
                                        char* __restrict__ ws)
{
  unsigned short* WdevH = (unsigned short*)(ws + WS_WDEV_H);
  unsigned short* WdevL = (unsigned short*)(ws + WS_WDEV_L);
  unsigned short* WH[3] = {(unsigned short*)(ws+WS_W1_H),(unsigned short*)(ws+WS_W2_H),(unsigned short*)(ws+WS_W3_H)};
  unsigned short* WL[3] = {(unsigned short*)(ws+WS_W1_L),(unsigned short*)(ws+WS_W2_L),(unsigned short*)(ws+WS_W3_L)};
  unsigned short* WaH = (unsigned short*)(ws + WS_WA_H);
  unsigned short* WaL = (unsigned short*)(ws + WS_WA_L);
  unsigned short* WfH = (unsigned short*)(ws + WS_WF_H);
  unsigned short* WfL = (unsigned short*)(ws + WS_WF_L);
  const int total = 2048 + 3*4096 + 8192 + 16384;
  for (int idx = blockIdx.x*256 + threadIdx.x; idx < total; idx += gridDim.x*256){
    if (idx < 2048){                       // Wdev (14x64), K padded to 32, NT=4
      int tt = idx;
      int frag = tt >> 9, within = tt & 511, lane = within >> 3, j = within & 7;
      int nt = frag & 3;
      int k = ((lane>>4)<<3) + j;
      int n = (nt<<4) + (lane & 15);
      float v = (k < 14) ? Wdev[k*64 + n] : 0.f;
      unsigned short h,l; split2(v,h,l); WdevH[tt]=h; WdevL[tt]=l;
    } else if (idx < 2048 + 3*4096){       // W1/W2/W3 (64x64), KS=2, NT=4
      int tt = idx - 2048; int Li = tt / 4096; int r = tt - Li*4096;
      int frag = r >> 9, within = r & 511, lane = within >> 3, j = within & 7;
      int ks = frag >> 2, nt = frag & 3;
      int k = (ks<<5) + ((lane>>4)<<3) + j;
      int n = (nt<<4) + (lane & 15);
      const float* W = (Li==0) ? W1 : ((Li==1) ? W2 : W3);
      float v = W[k*64 + n];
      unsigned short h,l; split2(v,h,l); WH[Li][r]=h; WL[Li][r]=l;
    } else if (idx < 2048 + 3*4096 + 8192){ // Wa = Wf1 rows 0..63 (64x128), KS=2, NT=8
      int r = idx - (2048 + 3*4096);
      int frag = r >> 9, within = r & 511, lane = within >> 3, j = within & 7;
      int ks = frag >> 3, nt = frag & 7;
      int k = (ks<<5) + ((lane>>4)<<3) + j;
      int n = (nt<<4) + (lane & 15);
      float v = Wf1[k*128 + n];
      unsigned short h,l; split2(v,h,l); WaH[r]=h; WaL[r]=l;
    } else {                                // Wfull = Wf1 rows 64..191 (128x128), KS=4, NT=8
      int r = idx - (2048 + 3*4096 + 8192);
      int frag = r >> 9, within = r & 511, lane = within >> 3, j = within & 7;
      int ks = frag >> 3, nt = frag & 7;
      int k = (ks<<5) + ((lane>>4)<<3) + j;
      int n = (nt<<4) + (lane & 15);
      float v = Wf1[(64 + k)*128 + n];
      unsigned short h,l; split2(v,h,l); WfH[r]=h; WfL[r]=l;
    }
  }
}

// ------------------------------------------------------------------
// fused PGCN critic. Exact R10 structure (champion: 346.6us, no spills)
// + R13 s_setprio(1) around MFMA clusters.
// R11/R12 lesson: ANY f32x2 packing or extra live state spills (~201MB
// scratch) — structure is ~2-5 regs below the (256,6) cap of 85.
// ------------------------------------------------------------------
extern "C" __global__ __launch_bounds__(256, 6)
void pgcn_fused(const float* __restrict__ dobs, const float* __restrict__ sobs,
                const float* __restrict__ adj,
                const float* __restrict__ bdev,
                const float* __restrict__ Wsrv, const float* __restrict__ bsrv,
                const float* __restrict__ b1, const float* __restrict__ b2,
                const float* __restrict__ b3,
                const float* __restrict__ bf1, const float* __restrict__ Wf2,
                const float* __restrict__ bf2,
                const char* __restrict__ ws, float* __restrict__ out)
{
  // hi plane: halfwords [0, 4608)  (64 rows x 72), lo plane: [4608, 9216); 18432 B
  __shared__ __align__(16) unsigned short     lds_Yr[9216];
  __shared__ __align__(16) unsigned long long lds_Abits[64];   // LIVE all layers
  __shared__ __align__(16) float    lds_d[64];                  // dead by head
  // ---- head-phase aliases (live only after the last GCN barrier) ----
  char* Yb = (char*)lds_Yr;
  float*          lds_mp  = (float*)(Yb + 16384);               // 1024 B
  float*          lds_srv = (float*)(Yb + 17408);               //  256 B
  float*          lds_s1  = (float*)(Yb + 17664);               //  512 B
  unsigned short* lds_Vl  = (unsigned short*)(Yb + 18176);      //  256 B
  unsigned short* lds_Vh  = (unsigned short*)lds_d;             //  256 B

  const int t = threadIdx.x;
  const int w = t >> 6;
  const int lane = t & 63;
  const int quad = lane >> 4;
  const int c = lane & 15;
  const long item = blockIdx.x;
  const bool isSrv = (w == 3) && (quad == 3);

  // ---------- stage adjacency as bitmask ----------
  {
    const f32x4* src = (const f32x4*)(adj + item*4096 + ((t>>2)<<6) + ((t&3)<<4));
    unsigned bits = 0;
    for (int i = 0; i < 4; ++i){
      f32x4 v = src[i];
      unsigned b = (v.x != 0.f) | (((unsigned)(v.y != 0.f))<<1)
                 | (((unsigned)(v.z != 0.f))<<2) | (((unsigned)(v.w != 0.f))<<3);
      bits |= b << (i<<2);
    }
    ((unsigned short*)lds_Abits)[t] = (unsigned short)bits;
  }

  // ---------- load device_obs rows as A-operand frags (hi/lo) ----------
  unsigned ahi[4] = {0,0,0,0}, alo[4] = {0,0,0,0};
  {
    int m = (w<<4) + c;
    if (quad < 2 && m < 63){
      const float* rp = dobs + item*882 + m*14 + (quad<<3);
      float e[8];
      f32x2 p0 = *(const f32x2*)(rp);
      f32x2 p1 = *(const f32x2*)(rp+2);
      f32x2 p2 = *(const f32x2*)(rp+4);
      e[0]=p0.x; e[1]=p0.y; e[2]=p1.x; e[3]=p1.y; e[4]=p2.x; e[5]=p2.y;
      if (quad == 0){
        f32x2 p3 = *(const f32x2*)(rp+6);
        e[6]=p3.x; e[7]=p3.y;
      } else {
        e[6]=0.f; e[7]=0.f;                   // k = 14,15 pad
      }
      for (int d0 = 0; d0 < 4; ++d0)
        split_pair(e[2*d0], e[2*d0+1], ahi[d0], alo[d0]);
    }
  }

  // ---------- early hoisted per-thread constants ----------
  float bdv0 = bdev[c], bdv1 = bdev[c+16], bdv2 = bdev[c+32], bdv3 = bdev[c+48];
  float srvv4[4];
  if (isSrv){
    float s0 = sobs[item*3+0], s1a = sobs[item*3+1], s2a = sobs[item*3+2];
#pragma unroll
    for (int nt = 0; nt < 4; ++nt){
      int col = c + (nt<<4);
      float v = s0*Wsrv[col] + s1a*Wsrv[64+col] + s2a*Wsrv[128+col] + bsrv[col];
      srvv4[nt] = fmaxf(v, 0.f);
    }
  }
  __syncthreads();   // [S1] bits ready

  // ---------- degrees from popcount ----------
  if (t < 64){
    unsigned long long mk = lds_Abits[t];
    int deg = __popcll(mk);
    lds_d[t] = 1.0f / sqrtf((float)(deg < 1 ? 1 : deg));
  }
  __syncthreads();   // [S2] d ready

  // LDS base offsets (bytes)
  const int ybw = (c*72 + (w<<4) + (quad<<2)) << 1;          // Y write (+2304*nt)
  const int yrd = (c*72 + (quad<<3)) << 1;                    // Y read  (+2304*mt+64*ks)
  const int zbw = (((w<<4)+c)*72 + (quad<<2)) << 1;           // Z write (+32*mt)
  const int zrd = (((w<<4)+c)*72 + (quad<<3)) << 1;           // Z read  (+64*ks)

  float hcur[4][4];

  // ---------- embed: x = relu(dobs@Wdev + bdev); row63 = server; write Y1 = d*x
  {
    f32x4 dE = *(const f32x4*)&lds_d[(w<<4) + (quad<<2)];
    U4 a_h, a_l;
    a_h.u = uint4v{ahi[0],ahi[1],ahi[2],ahi[3]};
    a_l.u = uint4v{alo[0],alo[1],alo[2],alo[3]};
    const uint4v* WdHp = (const uint4v*)(ws + WS_WDEV_H);
    const uint4v* WdLp = (const uint4v*)(ws + WS_WDEV_L);
#define EMB(NT, BB) { \
    U4 wh, wl; \
    wh.u = WdHp[(NT)*64 + lane]; wl.u = WdLp[(NT)*64 + lane]; \
    f32x4 g = {0.f,0.f,0.f,0.f}; \
    PRIO1; \
    g = mfma16(a_h, wh, g); \
    g = mfma16(a_h, wl, g); \
    g = mfma16(a_l, wh, g); \
    PRIO0; \
    float y0 = fmaxf(g[0] + (BB), 0.f); \
    float y1 = fmaxf(g[1] + (BB), 0.f); \
    float y2 = fmaxf(g[2] + (BB), 0.f); \
    float y3 = fmaxf(g[3] + (BB), 0.f); \
    if (isSrv) y3 = srvv4[NT];            /* node 63 = server embedding */ \
    y0 *= dE.x; y1 *= dE.y; y2 *= dE.z; y3 *= dE.w;       /* Y = d * x */ \
    unsigned h01,l01,h23,l23; \
    split_pair(y0, y1, h01, l01); \
    split_pair(y2, y3, h23, l23); \
    *(uint2v*)(Yb + ybw + 2304*(NT))        = uint2v{ h01, h23 }; \
    *(uint2v*)(Yb + ybw + 2304*(NT) + 9216) = uint2v{ l01, l23 }; }
    EMB(0, bdv0)
    EMB(1, bdv1)
    EMB(2, bdv2)
    EMB(3, bdv3)
#undef EMB
  }
  __syncthreads();   // Y1 ready

  // ---------- 3 GCN layers ----------
  const uint4v* WH_tab[3] = {(const uint4v*)(ws+WS_W1_H),(const uint4v*)(ws+WS_W2_H),(const uint4v*)(ws+WS_W3_H)};
  const uint4v* WL_tab[3] = {(const uint4v*)(ws+WS_W1_L),(const uint4v*)(ws+WS_W2_L),(const uint4v*)(ws+WS_W3_L)};
  const float* bias_tab[3] = {b1, b2, b3};

  for (int L = 0; L < 3; ++L){
    const uint4v* WHp = WH_tab[L];
    const uint4v* WLp = WL_tab[L];
    const float* bp = bias_tab[L];
    float bL0 = bp[c], bL1 = bp[c+16], bL2 = bp[c+32], bL3 = bp[c+48];
    float ddc = lds_d[(w<<4) + c];

    // atk re-derived per layer from LIVE Abits — live range = step1 only
    U4 atk0, atk1;
    {
      unsigned long long mk = lds_Abits[(w<<4) + c];
      unsigned by0 = (unsigned)(mk >> (quad<<3)) & 0xffu;
      unsigned by1 = (unsigned)(mk >> (32 + (quad<<3))) & 0xffu;
#pragma unroll
      for (int r = 0; r < 4; ++r){
        unsigned e0 = 0u - ((by0 >> (2*r)) & 1u);
        unsigned o0 = 0u - ((by0 >> (2*r+1)) & 1u);
        atk0.u[r] = (e0 & 0x3f80u) | (o0 & 0x3f800000u);
        unsigned e1 = 0u - ((by1 >> (2*r)) & 1u);
        unsigned o1 = 0u - ((by1 >> (2*r+1)) & 1u);
        atk1.u[r] = (e1 & 0x3f80u) | (o1 & 0x3f800000u);
      }
    }

    // step 1 (swapped): Zt = Yt @ At, depth-2 pipeline over mt (LDS reads only)
    f32x4 zacc0, zacc1, zacc2, zacc3;
    {
      U4 yAh0,yAl0,yAh1,yAl1, yBh0,yBl0,yBh1,yBl1;
#define LOADY(H0,L0,H1,L1, MT) \
      H0.u = *(const uint4v*)(Yb + yrd + 2304*(MT)); \
      L0.u = *(const uint4v*)(Yb + yrd + 2304*(MT) + 9216); \
      H1.u = *(const uint4v*)(Yb + yrd + 2304*(MT) + 64); \
      L1.u = *(const uint4v*)(Yb + yrd + 2304*(MT) + 64 + 9216);
#define ZSTEP(ZD, H0,L0,H1,L1) { \
      f32x4 g = {0.f,0.f,0.f,0.f}; \
      PRIO1; \
      g = mfma16(H0, atk0, g); \
      g = mfma16(L0, atk0, g); \
      g = mfma16(H1, atk1, g); \
      g = mfma16(L1, atk1, g); \
      PRIO0; \
      ZD = g; }
      LOADY(yAh0,yAl0,yAh1,yAl1, 0)
      LOADY(yBh0,yBl0,yBh1,yBl1, 1)
      ZSTEP(zacc0, yAh0,yAl0,yAh1,yAl1)
      LOADY(yAh0,yAl0,yAh1,yAl1, 2)
      ZSTEP(zacc1, yBh0,yBl0,yBh1,yBl1)
      LOADY(yBh0,yBl0,yBh1,yBl1, 3)
      ZSTEP(zacc2, yAh0,yAl0,yAh1,yAl1)
      ZSTEP(zacc3, yBh0,yBl0,yBh1,yBl1)
#undef LOADY
#undef ZSTEP
    }
    __syncthreads();  // [B2] all Y reads done; region reusable

    // prefetch step-3 weights nt=0 NOW: L2 latency hides under step-2 LDS work
    U4 w0h, w0l, w1h, w1l;
    w0h.u = WHp[0*64 + lane];
    w0l.u = WLp[0*64 + lane];
    w1h.u = WHp[4*64 + lane];
    w1l.u = WLp[4*64 + lane];

    // step 2: Z' = d*Zt, regroup into per-wave rows [16w+c][hidden] (planes)
    {
      unsigned h01,l01,h23,l23;
      split_pair(zacc0[0]*ddc, zacc0[1]*ddc, h01, l01);
      split_pair(zacc0[2]*ddc, zacc0[3]*ddc, h23, l23);
      *(uint2v*)(Yb + zbw +  0)        = uint2v{ h01, h23 };
      *(uint2v*)(Yb + zbw +  0 + 9216) = uint2v{ l01, l23 };
      split_pair(zacc1[0]*ddc, zacc1[1]*ddc, h01, l01);
      split_pair(zacc1[2]*ddc, zacc1[3]*ddc, h23, l23);
      *(uint2v*)(Yb + zbw + 32)        = uint2v{ h01, h23 };
      *(uint2v*)(Yb + zbw + 32 + 9216) = uint2v{ l01, l23 };
      split_pair(zacc2[0]*ddc, zacc2[1]*ddc, h01, l01);
      split_pair(zacc2[2]*ddc, zacc2[3]*ddc, h23, l23);
      *(uint2v*)(Yb + zbw + 64)        = uint2v{ h01, h23 };
      *(uint2v*)(Yb + zbw + 64 + 9216) = uint2v{ l01, l23 };
      split_pair(zacc3[0]*ddc, zacc3[1]*ddc, h01, l01);
      split_pair(zacc3[2]*ddc, zacc3[3]*ddc, h23, l23);
      *(uint2v*)(Yb + zbw + 96)        = uint2v{ h01, h23 };
      *(uint2v*)(Yb + zbw + 96 + 9216) = uint2v{ l01, l23 };
    }
    // wave-private rows: order LDS writes before reads WITHOUT draining vmcnt
    asm volatile("s_waitcnt lgkmcnt(0)" ::: "memory");
    U4 zh0, zl0, zh1, zl1;
    zh0.u = *(const uint4v*)(Yb + zrd);
    zl0.u = *(const uint4v*)(Yb + zrd + 9216);
    zh1.u = *(const uint4v*)(Yb + zrd + 64);
    zl1.u = *(const uint4v*)(Yb + zrd + 64 + 9216);

    // step 3: G = Z' @ W (3-pass split), h = relu(G + b); single W buffer
#define GSTEP(NT, BB) { \
    f32x4 g = {0.f,0.f,0.f,0.f}; \
    PRIO1; \
    g = mfma16(zh0, w0h, g); g = mfma16(zh0, w0l, g); g = mfma16(zl0, w0h, g); \
    g = mfma16(zh1, w1h, g); g = mfma16(zh1, w1l, g); g = mfma16(zl1, w1h, g); \
    PRIO0; \
    hcur[NT][0] = fmaxf(g[0] + (BB), 0.f); \
    hcur[NT][1] = fmaxf(g[1] + (BB), 0.f); \
    hcur[NT][2] = fmaxf(g[2] + (BB), 0.f); \
    hcur[NT][3] = fmaxf(g[3] + (BB), 0.f); }
#define LOADW(NT) \
    w0h.u = WHp[(NT)*64 + lane]; \
    w0l.u = WLp[(NT)*64 + lane]; \
    w1h.u = WHp[(4+(NT))*64 + lane]; \
    w1l.u = WLp[(4+(NT))*64 + lane];
    GSTEP(0, bL0)
    LOADW(1)
    GSTEP(1, bL1)
    LOADW(2)
    GSTEP(2, bL2)
    LOADW(3)
    GSTEP(3, bL3)
#undef GSTEP
#undef LOADW
    __syncthreads();  // [B3] all Z' reads done; region reusable

    if (L < 2){
      // step 4: write next Y = d * h into [hidden][node] planes
      f32x4 d4s = *(const f32x4*)&lds_d[(w<<4) + (quad<<2)];
      for (int nt = 0; nt < 4; ++nt){
        unsigned h01, l01, h23, l23;
        split_pair(hcur[nt][0]*d4s.x, hcur[nt][1]*d4s.y, h01, l01);
        split_pair(hcur[nt][2]*d4s.z, hcur[nt][3]*d4s.w, h23, l23);
        *(uint2v*)(Yb + ybw + 2304*nt)        = uint2v{ h01, h23 };
        *(uint2v*)(Yb + ybw + 2304*nt + 9216) = uint2v{ l01, l23 };
      }
      __syncthreads();  // next layer's Y ready
    }
  }

  // ---------- head ----------
  unsigned* zbuf = (unsigned*)Yb + (w<<10);          // per-wave 4 KB pi-swizzle slice
  const int piL = (lane>>2) | ((lane&3)<<4);
  const int s0L = (piL>>2) & 1;

  // col-sum partials (quad-reduced in-wave) + server row
  {
    float cs[4];
    for (int nt = 0; nt < 4; ++nt){
      float s = hcur[nt][0] + hcur[nt][1] + hcur[nt][2] + hcur[nt][3];
      if (isSrv){ s -= hcur[nt][3]; lds_srv[c + (nt<<4)] = hcur[nt][3]; }
      s += __shfl_xor(s, 16);
      s += __shfl_xor(s, 32);
      cs[nt] = s;
    }
    if (quad == 0)
      for (int nt = 0; nt < 4; ++nt) lds_mp[(w<<6) + c + (nt<<4)] = cs[nt];
  }
  // transpose h -> A-frags via pi-swizzled per-wave slice
  for (int nt = 0; nt < 4; ++nt){
    int ks = nt >> 1;
    int lcBase = (quad<<2) + ((((nt&1)<<1) + (c>>3)) << 4);
    int e = c & 7;
    for (int r = 0; r < 4; ++r){
      unsigned pk = pack_hl(hcur[nt][r]);
      int lane_c = lcBase + r;
      int pi = (lane_c>>2) | ((lane_c&3)<<4);
      int sel = ((e>>2) ^ (pi>>2)) & 1;
      zbuf[(ks<<9) + (pi<<3) + (sel<<2) + (e&3)] = pk;
    }
  }
  __syncthreads();  // [Bh1] partials + srv + zbuf writes done; lds_d dead now

  // hoist epilogue constants (global, independent of the barriers)
  float wf2v[8];
#pragma unroll
  for (int nt = 0; nt < 8; ++nt) wf2v[nt] = Wf2[c + (nt<<4)];
  const float bb2 = bf2[0];

  // V = [mean(63 dev rows); srv] split to bf16 hi/lo (Vh aliases dead lds_d)
  if (t < 64){
    float mv = (lds_mp[t] + lds_mp[64+t] + lds_mp[128+t] + lds_mp[192+t]) * (1.0f/63.0f);
    unsigned short h,l; split2(mv,h,l);
    lds_Vh[t]=h; lds_Vl[t]=l;
  } else if (t < 128){
    float sv = lds_srv[t-64];
    unsigned short h,l; split2(sv,h,l);
    lds_Vh[t]=h; lds_Vl[t]=l;
  }
  __syncthreads();  // [Bh2] V ready; zbuf reads safe

  // read back h A-frags (issue all 4 LDS reads, then unpack)
  U4 hh0, hh1, hl0, hl1;
  {
    uint4v qa0 = *(const uint4v*)&zbuf[(0<<9) + (piL<<3) + (s0L<<2)];
    uint4v qb0 = *(const uint4v*)&zbuf[(0<<9) + (piL<<3) + ((1-s0L)<<2)];
    uint4v qa1 = *(const uint4v*)&zbuf[(1<<9) + (piL<<3) + (s0L<<2)];
    uint4v qb1 = *(const uint4v*)&zbuf[(1<<9) + (piL<<3) + ((1-s0L)<<2)];
    hh0.u = uint4v{ (qa0.y<<16)|(qa0.x&0xffffu), (qa0.w<<16)|(qa0.z&0xffffu),
                    (qb0.y<<16)|(qb0.x&0xffffu), (qb0.w<<16)|(qb0.z&0xffffu) };
    hl0.u = uint4v{ (qa0.y&0xffff0000u)|(qa0.x>>16), (qa0.w&0xffff0000u)|(qa0.z>>16),
                    (qb0.y&0xffff0000u)|(qb0.x>>16), (qb0.w&0xffff0000u)|(qb0.z>>16) };
    hh1.u = uint4v{ (qa1.y<<16)|(qa1.x&0xffffu), (qa1.w<<16)|(qa1.z&0xffffu),
                    (qb1.y<<16)|(qb1.x&0xffffu), (qb1.w<<16)|(qb1.z&0xffffu) };
    hl1.u = uint4v{ (qa1.y&0xffff0000u)|(qa1.x>>16), (qa1.w&0xffff0000u)|(qa1.z>>16),
                    (qb1.y&0xffff0000u)|(qb1.x>>16), (qb1.w&0xffff0000u)|(qb1.z>>16) };
  }

  // s1 = V @ Wfull + bf1 via MFMA (row 0 only); wave w owns cols 32w..32w+31
  {
    const uint4v* WfHp = (const uint4v*)(ws + WS_WF_H);
    const uint4v* WfLp = (const uint4v*)(ws + WS_WF_L);
    const int nt0 = (w<<1);
    float bf1a = 0.f, bf1b = 0.f;
    if (quad == 0){ bf1a = bf1[c + (w<<5)]; bf1b = bf1[c + (w<<5) + 16]; }
    f32x4 sacc0 = {0.f,0.f,0.f,0.f}, sacc1 = {0.f,0.f,0.f,0.f};
    for (int ks = 0; ks < 4; ++ks){
      U4 vh, vl;
      vh.u = *(const uint4v*)((const char*)lds_Vh + (ks<<6) + (quad<<4));
      vl.u = *(const uint4v*)((const char*)lds_Vl + (ks<<6) + (quad<<4));
      if (c != 0){ vh.u = uint4v{0,0,0,0}; vl.u = uint4v{0,0,0,0}; }
      U4 wh, wl;
      wh.u = WfHp[((ks<<3)+nt0)*64 + lane];
      wl.u = WfLp[((ks<<3)+nt0)*64 + lane];
      PRIO1;
      sacc0 = mfma16(vh, wh, sacc0);
      sacc0 = mfma16(vh, wl, sacc0);
      sacc0 = mfma16(vl, wh, sacc0);
      PRIO0;
      wh.u = WfHp[((ks<<3)+nt0+1)*64 + lane];
      wl.u = WfLp[((ks<<3)+nt0+1)*64 + lane];
      PRIO1;
      sacc1 = mfma16(vh, wh, sacc1);
      sacc1 = mfma16(vh, wl, sacc1);
      sacc1 = mfma16(vl, wh, sacc1);
      PRIO0;
    }
    if (quad == 0){
      int col0 = c + (w<<5);
      lds_s1[col0]      = sacc0[0] + bf1a;
      lds_s1[col0 + 16] = sacc1[0] + bf1b;
    }
  }
  __syncthreads();  // [Bh3] s1 ready

  // P = h @ Wa (3-pass split), single W buffer;
  // epilogue: out_n = sum_j relu(P+s1)[j]*Wf2[j]
  const uint4v* WaHp = (const uint4v*)(ws + WS_WA_H);
  const uint4v* WaLp = (const uint4v*)(ws + WS_WA_L);
  float s1v[8];
#pragma unroll
  for (int nt = 0; nt < 8; ++nt) s1v[nt] = lds_s1[c + (nt<<4)];
  float outacc[4] = {0.f,0.f,0.f,0.f};
#pragma unroll
  for (int nt = 0; nt < 8; ++nt){
    f32x4 g = {0.f,0.f,0.f,0.f};
    U4 wh, wl;
    wh.u = WaHp[nt*64 + lane];
    wl.u = WaLp[nt*64 + lane];
    PRIO1;
    g = mfma16(hh0, wh, g); g = mfma16(hh0, wl, g); g = mfma16(hl0, wh, g);
    PRIO0;
    wh.u = WaHp[(8+nt)*64 + lane];
    wl.u = WaLp[(8+nt)*64 + lane];
    PRIO1;
    g = mfma16(hh1, wh, g); g = mfma16(hh1, wl, g); g = mfma16(hl1, wh, g);
    PRIO0;
    float sv = s1v[nt]; float w2 = wf2v[nt];
    outacc[0] += fmaxf(g[0] + sv, 0.f) * w2;
    outacc[1] += fmaxf(g[1] + sv, 0.f) * w2;
    outacc[2] += fmaxf(g[2] + sv, 0.f) * w2;
    outacc[3] += fmaxf(g[3] + sv, 0.f) * w2;
  }
  {
    float bb = bb2;
#pragma unroll
    for (int r = 0; r < 4; ++r){
      float v = outacc[r];
      v += __shfl_xor(v, 1); v += __shfl_xor(v, 2);
      v += __shfl_xor(v, 4); v += __shfl_xor(v, 8);
      if (c == 0){
        int row = (w<<4) + (quad<<2) + r;
        if (row < 63) out[item*63 + row] = v + bb;
      }
    }
  }
}

extern "C" void kernel_launch(void* const* d_in, const int* in_sizes, int n_in,
                              void* d_out, int out_size, void* d_ws, size_t ws_size,
                              hipStream_t stream)
{
  const float* dobs = (const float*)d_in[0];
  const float* sobs = (const float*)d_in[1];
  const float* adj  = (const float*)d_in[2];
  const float* Wdev = (const float*)d_in[3];
  const float* bdev = (const float*)d_in[4];
  const float* Wsrv = (const float*)d_in[5];
  const float* bsrv = (const float*)d_in[6];
  const float* W1   = (const float*)d_in[7];
  const float* b1   = (const float*)d_in[8];
  const float* W2   = (const float*)d_in[9];
  const float* b2   = (const float*)d_in[10];
  const float* W3   = (const float*)d_in[11];
  const float* b3   = (const float*)d_in[12];
  const float* Wf1  = (const float*)d_in[13];
  const float* bf1  = (const float*)d_in[14];
  const float* Wf2  = (const float*)d_in[15];
  const float* bf2  = (const float*)d_in[16];
  float* out = (float*)d_out;
  char* ws = (char*)d_ws;
  int nb = in_sizes[1] / 3;   // batch size (server_obs is B x 3)

  prep_weights<<<dim3(160), dim3(256), 0, stream>>>(Wdev, W1, W2, W3, Wf1, ws);
  pgcn_fused<<<dim3(nb), dim3(256), 0, stream>>>(dobs, sobs, adj, bdev, Wsrv, bsrv,
                                                 b1, b2, b3, bf1, Wf2, bf2, ws, out);
}

// Round 8
// 610.887 us; speedup vs baseline: 1.1357x; 1.0268x over previous
//
#include <hip/hip_runtime.h>
#include <hip/hip_bf16.h>
#include <stdint.h>

typedef __attribute__((ext_vector_type(8))) __bf16 bf16x8;
typedef __attribute__((ext_vector_type(4))) float f32x4;
typedef __attribute__((ext_vector_type(2))) float f32x2;
typedef __attribute__((ext_vector_type(4))) unsigned uint4v;
typedef __attribute__((ext_vector_type(2))) unsigned uint2v;

union U4 { uint4v u; bf16x8 b; };

// ---- d_ws layout (bytes) ----
#define WS_WDEV_H 0
#define WS_WDEV_L 4096
#define WS_W1_H   8192
#define WS_W1_L   16384
#define WS_W2_H   24576
#define WS_W2_L   32768
#define WS_W3_H   40960
#define WS_W3_L   49152
#define WS_WA_H   57344
#define WS_WA_L   73728
#define WS_WF_H   90112
#define WS_WF_L   122880
// total 155648 bytes

__device__ __forceinline__ unsigned short f2bf(float f){
  union { float f; unsigned u; } v; v.f = f;
  unsigned r = v.u + 0x7fffu + ((v.u >> 16) & 1u);
  return (unsigned short)(r >> 16);
}
__device__ __forceinline__ float bf2f(unsigned short h){
  union { unsigned u; float f; } v; v.u = ((unsigned)h) << 16; return v.f;
}
__device__ __forceinline__ void split2(float x, unsigned short& hi, unsigned short& lo){
  hi = f2bf(x);
  lo = f2bf(x - bf2f(hi));   // exact residual
}
__device__ __forceinline__ f32x4 mfma16(const U4& a, const U4& b, f32x4 c){
  return __builtin_amdgcn_mfma_f32_16x16x32_bf16(a.b, b.b, c, 0, 0, 0);
}

// ---- HW packed bf16 conversion (v_cvt_pk_bf16_f32, RNE — bit-identical to rnu) ----
__device__ __forceinline__ unsigned cvt_pk_bf(float a, float b){
  float2 p; p.x = a; p.y = b;
  union { __hip_bfloat162 h; unsigned u; } cv;
  cv.h = __float22bfloat162_rn(p);          // low16 = bf(a), high16 = bf(b)
  return cv.u;
}
// hi2 = (bf16(x1)<<16)|bf16(x0), lo2 = same for RN residuals
__device__ __forceinline__ void split_pair(float x0, float x1, unsigned& hi2, unsigned& lo2){
  hi2 = cvt_pk_bf(x0, x1);
  lo2 = cvt_pk_bf(x0 - __uint_as_float(hi2 << 16),
                  x1 - __uint_as_float(hi2 & 0xffff0000u));
}
// (lo16<<16)|hi16 for one value (head zbuf element format)
__device__ __forceinline__ unsigned pack_hl(float z){
  unsigned h = cvt_pk_bf(z, 0.f) & 0xffffu;
  float r = z - __uint_as_float(h << 16);
  return (cvt_pk_bf(0.f, r) & 0xffff0000u) | h;
}

// ------------------------------------------------------------------
// prep kernel: weights -> hi/lo bf16 MFMA B-fragments.
// B-frag: idx = ((ks*NT+nt)*64 + lane)*8 + j ; k = ks*32+(lane>>4)*8+j, n = nt*16+(lane&15)
// ------------------------------------------------------------------
extern "C" __global__ void prep_weights(const float* __restrict__ Wdev,
                                        const float* __restrict__ W1,
                                        const float* __restrict__ W2,
                                        const float* __restrict__ W3,
                                        const float* __restrict__ Wf1,
                                        char* __restrict__ ws)
{
  unsigned short* WdevH = (unsigned short*)(ws + WS_WDEV_H);
  unsigned short* WdevL = (unsigned short*)(ws + WS_WDEV_L);
  unsigned short* WH[3] = {(unsigned short*)(ws+WS_W1_H),(unsigned short*)(ws+WS_W2_H),(unsigned short*)(ws+WS_W3_H)};
  unsigned short* WL[3] = {(unsigned short*)(ws+WS_W1_L),(unsigned short*)(ws+WS_W2_L),(unsigned short*)(ws+WS_W3_L)};
  unsigned short* WaH = (unsigned short*)(ws + WS_WA_H);
  unsigned short* WaL = (unsigned short*)(ws + WS_WA_L);
  unsigned short* WfH = (unsigned short*)(ws + WS_WF_H);
  unsigned short* WfL = (unsigned short*)(ws + WS_WF_L);
  const int total = 2048 + 3*4096 + 8192 + 16384;
  for (int idx = blockIdx.x*256 + threadIdx.x; idx < total; idx += gridDim.x*256){
    if (idx < 2048){                       // Wdev (14x64), K padded to 32, NT=4
      int tt = idx;
      int frag = tt >> 9, within = tt & 511, lane = within >> 3, j = within & 7;
      int nt = frag & 3;
      int k = ((lane>>4)<<3) + j;
      int n = (nt<<4) + (lane & 15);
      float v = (k < 14) ? Wdev[k*64 + n] : 0.f;
      unsigned short h,l; split2(v,h,l); WdevH[tt]=h; WdevL[tt]=l;
    } else if (idx < 2048 + 3*4096){       // W1/W2/W3 (64x64), KS=2, NT=4
      int tt = idx - 2048; int Li = tt / 4096; int r = tt - Li*4096;
      int frag = r >> 9, within = r & 511, lane = within >> 3, j = within & 7;
      int ks = frag >> 2, nt = frag & 3;
      int k = (ks<<5) + ((lane>>4)<<3) + j;
      int n = (nt<<4) + (lane & 15);
      const float* W = (Li==0) ? W1 : ((Li==1) ? W2 : W3);
      float v = W[k*64 + n];
      unsigned short h,l; split2(v,h,l); WH[Li][r]=h; WL[Li][r]=l;
    } else if (idx < 2048 + 3*4096 + 8192){ // Wa = Wf1 rows 0..63 (64x128), KS=2, NT=8
      int r = idx - (2048 + 3*4096);
      int frag = r >> 9, within = r & 511, lane = within >> 3, j = within & 7;
      int ks = frag >> 3, nt = frag & 7;
      int k = (ks<<5) + ((lane>>4)<<3) + j;
      int n = (nt<<4) + (lane & 15);
      float v = Wf1[k*128 + n];
      unsigned short h,l; split2(v,h,l); WaH[r]=h; WaL[r]=l;
    } else {                                // Wfull = Wf1 rows 64..191 (128x128), KS=4, NT=8
      int r = idx - (2048 + 3*4096 + 8192);
      int frag = r >> 9, within = r & 511, lane = within >> 3, j = within & 7;
      int ks = frag >> 3, nt = frag & 7;
      int k = (ks<<5) + ((lane>>4)<<3) + j;
      int n = (nt<<4) + (lane & 15);
      float v = Wf1[(64 + k)*128 + n];
      unsigned short h,l; split2(v,h,l); WfH[r]=h; WfL[r]=l;
    }
  }
}

// ------------------------------------------------------------------
// fused PGCN critic, transposed-first-matmul scheme + R10 register diet.
// R14 = exact R10 restore (champion: 346.6us, WRITE 4.5MB, no spills).
// Session ledger: R7 ILP(+clamp) 368; R8 clamp8 spill 675; R9 clamp6+ILP
// spill 502; R10 diet 346.6; R11 full-pack spill 427; R12 partial-pack
// spill 411; R13 setprio minor-spill 358. The structure is exactly
// register-critical at the (256,6) cap of ~85 unified regs: ANY added
// live state, f32x2 pair constraint, or scheduling pin (setprio) spills.
// R10 is the stable operating point.
// ------------------------------------------------------------------
extern "C" __global__ __launch_bounds__(256, 6)
void pgcn_fused(const float* __restrict__ dobs, const float* __restrict__ sobs,
                const float* __restrict__ adj,
                const float* __restrict__ bdev,
                const float* __restrict__ Wsrv, const float* __restrict__ bsrv,
                const float* __restrict__ b1, const float* __restrict__ b2,
                const float* __restrict__ b3,
                const float* __restrict__ bf1, const float* __restrict__ Wf2,
                const float* __restrict__ bf2,
                const char* __restrict__ ws, float* __restrict__ out)
{
  // hi plane: halfwords [0, 4608)  (64 rows x 72), lo plane: [4608, 9216); 18432 B
  __shared__ __align__(16) unsigned short     lds_Yr[9216];
  __shared__ __align__(16) unsigned long long lds_Abits[64];   // LIVE all layers
  __shared__ __align__(16) float    lds_d[64];                  // dead by head
  // ---- head-phase aliases (live only after the last GCN barrier) ----
  // zbuf uses Yb[0..16384); Yb[16384..18432) = mp(1024)+srv(256)+s1(512)+Vl(256)
  // Vh aliases lds_d (dd/ddc last read at L=2 step2, before head).
  char* Yb = (char*)lds_Yr;
  float*          lds_mp  = (float*)(Yb + 16384);               // 1024 B
  float*          lds_srv = (float*)(Yb + 17408);               //  256 B
  float*          lds_s1  = (float*)(Yb + 17664);               //  512 B
  unsigned short* lds_Vl  = (unsigned short*)(Yb + 18176);      //  256 B
  unsigned short* lds_Vh  = (unsigned short*)lds_d;             //  256 B

  const int t = threadIdx.x;
  const int w = t >> 6;
  const int lane = t & 63;
  const int quad = lane >> 4;
  const int c = lane & 15;
  const long item = blockIdx.x;
  const bool isSrv = (w == 3) && (quad == 3);

  // ---------- stage adjacency as bitmask ----------
  {
    const f32x4* src = (const f32x4*)(adj + item*4096 + ((t>>2)<<6) + ((t&3)<<4));
    unsigned bits = 0;
    for (int i = 0; i < 4; ++i){
      f32x4 v = src[i];
      unsigned b = (v.x != 0.f) | (((unsigned)(v.y != 0.f))<<1)
                 | (((unsigned)(v.z != 0.f))<<2) | (((unsigned)(v.w != 0.f))<<3);
      bits |= b << (i<<2);
    }
    ((unsigned short*)lds_Abits)[t] = (unsigned short)bits;
  }

  // ---------- load device_obs rows as A-operand frags (hi/lo) ----------
  unsigned ahi[4] = {0,0,0,0}, alo[4] = {0,0,0,0};
  {
    int m = (w<<4) + c;
    if (quad < 2 && m < 63){
      const float* rp = dobs + item*882 + m*14 + (quad<<3);
      float e[8];
      f32x2 p0 = *(const f32x2*)(rp);
      f32x2 p1 = *(const f32x2*)(rp+2);
      f32x2 p2 = *(const f32x2*)(rp+4);
      e[0]=p0.x; e[1]=p0.y; e[2]=p1.x; e[3]=p1.y; e[4]=p2.x; e[5]=p2.y;
      if (quad == 0){
        f32x2 p3 = *(const f32x2*)(rp+6);
        e[6]=p3.x; e[7]=p3.y;
      } else {
        e[6]=0.f; e[7]=0.f;                   // k = 14,15 pad
      }
      for (int d0 = 0; d0 < 4; ++d0)
        split_pair(e[2*d0], e[2*d0+1], ahi[d0], alo[d0]);
    }
  }

  // ---------- early hoisted per-thread constants ----------
  float bdv0 = bdev[c], bdv1 = bdev[c+16], bdv2 = bdev[c+32], bdv3 = bdev[c+48];
  float srvv4[4];
  if (isSrv){
    float s0 = sobs[item*3+0], s1a = sobs[item*3+1], s2a = sobs[item*3+2];
#pragma unroll
    for (int nt = 0; nt < 4; ++nt){
      int col = c + (nt<<4);
      float v = s0*Wsrv[col] + s1a*Wsrv[64+col] + s2a*Wsrv[128+col] + bsrv[col];
      srvv4[nt] = fmaxf(v, 0.f);
    }
  }
  __syncthreads();   // [S1] bits ready

  // ---------- degrees from popcount ----------
  if (t < 64){
    unsigned long long mk = lds_Abits[t];
    int deg = __popcll(mk);
    lds_d[t] = 1.0f / sqrtf((float)(deg < 1 ? 1 : deg));
  }
  __syncthreads();   // [S2] d ready

  // LDS base offsets (bytes)
  const int ybw = (c*72 + (w<<4) + (quad<<2)) << 1;          // Y write (+2304*nt)
  const int yrd = (c*72 + (quad<<3)) << 1;                    // Y read  (+2304*mt+64*ks)
  const int zbw = (((w<<4)+c)*72 + (quad<<2)) << 1;           // Z write (+32*mt)
  const int zrd = (((w<<4)+c)*72 + (quad<<3)) << 1;           // Z read  (+64*ks)

  float hcur[4][4];

  // ---------- embed: x = relu(dobs@Wdev + bdev); row63 = server; write Y1 = d*x
  {
    // d for this thread's 4 output rows (phase-local, dies at embed end)
    f32x4 dE = *(const f32x4*)&lds_d[(w<<4) + (quad<<2)];
    U4 a_h, a_l;
    a_h.u = uint4v{ahi[0],ahi[1],ahi[2],ahi[3]};
    a_l.u = uint4v{alo[0],alo[1],alo[2],alo[3]};
    const uint4v* WdHp = (const uint4v*)(ws + WS_WDEV_H);
    const uint4v* WdLp = (const uint4v*)(ws + WS_WDEV_L);
#define EMB(NT, BB) { \
    U4 wh, wl; \
    wh.u = WdHp[(NT)*64 + lane]; wl.u = WdLp[(NT)*64 + lane]; \
    f32x4 g = {0.f,0.f,0.f,0.f}; \
    g = mfma16(a_h, wh, g); \
    g = mfma16(a_h, wl, g); \
    g = mfma16(a_l, wh, g); \
    float y0 = fmaxf(g[0] + (BB), 0.f); \
    float y1 = fmaxf(g[1] + (BB), 0.f); \
    float y2 = fmaxf(g[2] + (BB), 0.f); \
    float y3 = fmaxf(g[3] + (BB), 0.f); \
    if (isSrv) y3 = srvv4[NT];            /* node 63 = server embedding */ \
    y0 *= dE.x; y1 *= dE.y; y2 *= dE.z; y3 *= dE.w;       /* Y = d * x */ \
    unsigned h01,l01,h23,l23; \
    split_pair(y0, y1, h01, l01); \
    split_pair(y2, y3, h23, l23); \
    *(uint2v*)(Yb + ybw + 2304*(NT))        = uint2v{ h01, h23 }; \
    *(uint2v*)(Yb + ybw + 2304*(NT) + 9216) = uint2v{ l01, l23 }; }
    EMB(0, bdv0)
    EMB(1, bdv1)
    EMB(2, bdv2)
    EMB(3, bdv3)
#undef EMB
  }
  __syncthreads();   // Y1 ready

  // ---------- 3 GCN layers ----------
  const uint4v* WH_tab[3] = {(const uint4v*)(ws+WS_W1_H),(const uint4v*)(ws+WS_W2_H),(const uint4v*)(ws+WS_W3_H)};
  const uint4v* WL_tab[3] = {(const uint4v*)(ws+WS_W1_L),(const uint4v*)(ws+WS_W2_L),(const uint4v*)(ws+WS_W3_L)};
  const float* bias_tab[3] = {b1, b2, b3};

  for (int L = 0; L < 3; ++L){
    const uint4v* WHp = WH_tab[L];
    const uint4v* WLp = WL_tab[L];
    const float* bp = bias_tab[L];
    // bias hoist: issued at layer top, consumed in step-3 epilogue
    float bL0 = bp[c], bL1 = bp[c+16], bL2 = bp[c+32], bL3 = bp[c+48];
    // d for step2 (1 reg, issued early so LDS latency hides under step1)
    float ddc = lds_d[(w<<4) + c];

    // atk re-derived per layer from LIVE Abits — live range = step1 only
    U4 atk0, atk1;
    {
      unsigned long long mk = lds_Abits[(w<<4) + c];
      unsigned by0 = (unsigned)(mk >> (quad<<3)) & 0xffu;
      unsigned by1 = (unsigned)(mk >> (32 + (quad<<3))) & 0xffu;
#pragma unroll
      for (int r = 0; r < 4; ++r){
        unsigned e0 = 0u - ((by0 >> (2*r)) & 1u);
        unsigned o0 = 0u - ((by0 >> (2*r+1)) & 1u);
        atk0.u[r] = (e0 & 0x3f80u) | (o0 & 0x3f800000u);
        unsigned e1 = 0u - ((by1 >> (2*r)) & 1u);
        unsigned o1 = 0u - ((by1 >> (2*r+1)) & 1u);
        atk1.u[r] = (e1 & 0x3f80u) | (o1 & 0x3f800000u);
      }
    }

    // step 1 (swapped): Zt = Yt @ At, depth-2 pipeline over mt (LDS reads only)
    f32x4 zacc0, zacc1, zacc2, zacc3;
    {
      U4 yAh0,yAl0,yAh1,yAl1, yBh0,yBl0,yBh1,yBl1;
#define LOADY(H0,L0,H1,L1, MT) \
      H0.u = *(const uint4v*)(Yb + yrd + 2304*(MT)); \
      L0.u = *(const uint4v*)(Yb + yrd + 2304*(MT) + 9216); \
      H1.u = *(const uint4v*)(Yb + yrd + 2304*(MT) + 64); \
      L1.u = *(const uint4v*)(Yb + yrd + 2304*(MT) + 64 + 9216);
#define ZSTEP(ZD, H0,L0,H1,L1) { \
      f32x4 g = {0.f,0.f,0.f,0.f}; \
      g = mfma16(H0, atk0, g); \
      g = mfma16(L0, atk0, g); \
      g = mfma16(H1, atk1, g); \
      g = mfma16(L1, atk1, g); \
      ZD = g; }
      LOADY(yAh0,yAl0,yAh1,yAl1, 0)
      LOADY(yBh0,yBl0,yBh1,yBl1, 1)
      ZSTEP(zacc0, yAh0,yAl0,yAh1,yAl1)
      LOADY(yAh0,yAl0,yAh1,yAl1, 2)
      ZSTEP(zacc1, yBh0,yBl0,yBh1,yBl1)
      LOADY(yBh0,yBl0,yBh1,yBl1, 3)
      ZSTEP(zacc2, yAh0,yAl0,yAh1,yAl1)
      ZSTEP(zacc3, yBh0,yBl0,yBh1,yBl1)
#undef LOADY
#undef ZSTEP
    }
    __syncthreads();  // [B2] all Y reads done; region reusable

    // prefetch step-3 weights nt=0 NOW: L2 latency hides under step-2 LDS work
    U4 w0h, w0l, w1h, w1l;
    w0h.u = WHp[0*64 + lane];
    w0l.u = WLp[0*64 + lane];
    w1h.u = WHp[4*64 + lane];
    w1l.u = WLp[4*64 + lane];

    // step 2: Z' = d*Zt, regroup into per-wave rows [16w+c][hidden] (planes)
    {
      unsigned h01,l01,h23,l23;
      split_pair(zacc0[0]*ddc, zacc0[1]*ddc, h01, l01);
      split_pair(zacc0[2]*ddc, zacc0[3]*ddc, h23, l23);
      *(uint2v*)(Yb + zbw +  0)        = uint2v{ h01, h23 };
      *(uint2v*)(Yb + zbw +  0 + 9216) = uint2v{ l01, l23 };
      split_pair(zacc1[0]*ddc, zacc1[1]*ddc, h01, l01);
      split_pair(zacc1[2]*ddc, zacc1[3]*ddc, h23, l23);
      *(uint2v*)(Yb + zbw + 32)        = uint2v{ h01, h23 };
      *(uint2v*)(Yb + zbw + 32 + 9216) = uint2v{ l01, l23 };
      split_pair(zacc2[0]*ddc, zacc2[1]*ddc, h01, l01);
      split_pair(zacc2[2]*ddc, zacc2[3]*ddc, h23, l23);
      *(uint2v*)(Yb + zbw + 64)        = uint2v{ h01, h23 };
      *(uint2v*)(Yb + zbw + 64 + 9216) = uint2v{ l01, l23 };
      split_pair(zacc3[0]*ddc, zacc3[1]*ddc, h01, l01);
      split_pair(zacc3[2]*ddc, zacc3[3]*ddc, h23, l23);
      *(uint2v*)(Yb + zbw + 96)        = uint2v{ h01, h23 };
      *(uint2v*)(Yb + zbw + 96 + 9216) = uint2v{ l01, l23 };
    }
    // wave-private rows: order LDS writes before reads WITHOUT draining vmcnt
    asm volatile("s_waitcnt lgkmcnt(0)" ::: "memory");
    U4 zh0, zl0, zh1, zl1;
    zh0.u = *(const uint4v*)(Yb + zrd);
    zl0.u = *(const uint4v*)(Yb + zrd + 9216);
    zh1.u = *(const uint4v*)(Yb + zrd + 64);
    zl1.u = *(const uint4v*)(Yb + zrd + 64 + 9216);

    // step 3: G = Z' @ W (3-pass split), h = relu(G + b); single W buffer
#define GSTEP(NT, BB) { \
    f32x4 g = {0.f,0.f,0.f,0.f}; \
    g = mfma16(zh0, w0h, g); g = mfma16(zh0, w0l, g); g = mfma16(zl0, w0h, g); \
    g = mfma16(zh1, w1h, g); g = mfma16(zh1, w1l, g); g = mfma16(zl1, w1h, g); \
    hcur[NT][0] = fmaxf(g[0] + (BB), 0.f); \
    hcur[NT][1] = fmaxf(g[1] + (BB), 0.f); \
    hcur[NT][2] = fmaxf(g[2] + (BB), 0.f); \
    hcur[NT][3] = fmaxf(g[3] + (BB), 0.f); }
#define LOADW(NT) \
    w0h.u = WHp[(NT)*64 + lane]; \
    w0l.u = WLp[(NT)*64 + lane]; \
    w1h.u = WHp[(4+(NT))*64 + lane]; \
    w1l.u = WLp[(4+(NT))*64 + lane];
    GSTEP(0, bL0)
    LOADW(1)
    GSTEP(1, bL1)
    LOADW(2)
    GSTEP(2, bL2)
    LOADW(3)
    GSTEP(3, bL3)
#undef GSTEP
#undef LOADW
    __syncthreads();  // [B3] all Z' reads done; region reusable

    if (L < 2){
      // step 4: write next Y = d * h into [hidden][node] planes
      f32x4 d4s = *(const f32x4*)&lds_d[(w<<4) + (quad<<2)];
      for (int nt = 0; nt < 4; ++nt){
        unsigned h01, l01, h23, l23;
        split_pair(hcur[nt][0]*d4s.x, hcur[nt][1]*d4s.y, h01, l01);
        split_pair(hcur[nt][2]*d4s.z, hcur[nt][3]*d4s.w, h23, l23);
        *(uint2v*)(Yb + ybw + 2304*nt)        = uint2v{ h01, h23 };
        *(uint2v*)(Yb + ybw + 2304*nt + 9216) = uint2v{ l01, l23 };
      }
      __syncthreads();  // next layer's Y ready
    }
  }

  // ---------- head ----------
  unsigned* zbuf = (unsigned*)Yb + (w<<10);          // per-wave 4 KB pi-swizzle slice
  const int piL = (lane>>2) | ((lane&3)<<4);
  const int s0L = (piL>>2) & 1;

  // col-sum partials (quad-reduced in-wave) + server row
  {
    float cs[4];
    for (int nt = 0; nt < 4; ++nt){
      float s = hcur[nt][0] + hcur[nt][1] + hcur[nt][2] + hcur[nt][3];
      if (isSrv){ s -= hcur[nt][3]; lds_srv[c + (nt<<4)] = hcur[nt][3]; }
      s += __shfl_xor(s, 16);
      s += __shfl_xor(s, 32);
      cs[nt] = s;
    }
    if (quad == 0)
      for (int nt = 0; nt < 4; ++nt) lds_mp[(w<<6) + c + (nt<<4)] = cs[nt];
  }
  // transpose h -> A-frags via pi-swizzled per-wave slice
  for (int nt = 0; nt < 4; ++nt){
    int ks = nt >> 1;
    int lcBase = (quad<<2) + ((((nt&1)<<1) + (c>>3)) << 4);
    int e = c & 7;
    for (int r = 0; r < 4; ++r){
      unsigned pk = pack_hl(hcur[nt][r]);
      int lane_c = lcBase + r;
      int pi = (lane_c>>2) | ((lane_c&3)<<4);
      int sel = ((e>>2) ^ (pi>>2)) & 1;
      zbuf[(ks<<9) + (pi<<3) + (sel<<2) + (e&3)] = pk;
    }
  }
  __syncthreads();  // [Bh1] partials + srv + zbuf writes done; lds_d dead now

  // hoist epilogue constants (global, independent of the barriers)
  float wf2v[8];
#pragma unroll
  for (int nt = 0; nt < 8; ++nt) wf2v[nt] = Wf2[c + (nt<<4)];
  const float bb2 = bf2[0];

  // V = [mean(63 dev rows); srv] split to bf16 hi/lo (Vh aliases dead lds_d)
  if (t < 64){
    float mv = (lds_mp[t] + lds_mp[64+t] + lds_mp[128+t] + lds_mp[192+t]) * (1.0f/63.0f);
    unsigned short h,l; split2(mv,h,l);
    lds_Vh[t]=h; lds_Vl[t]=l;
  } else if (t < 128){
    float sv = lds_srv[t-64];
    unsigned short h,l; split2(sv,h,l);
    lds_Vh[t]=h; lds_Vl[t]=l;
  }
  __syncthreads();  // [Bh2] V ready; zbuf reads safe

  // read back h A-frags (issue all 4 LDS reads, then unpack)
  U4 hh0, hh1, hl0, hl1;
  {
    uint4v qa0 = *(const uint4v*)&zbuf[(0<<9) + (piL<<3) + (s0L<<2)];
    uint4v qb0 = *(const uint4v*)&zbuf[(0<<9) + (piL<<3) + ((1-s0L)<<2)];
    uint4v qa1 = *(const uint4v*)&zbuf[(1<<9) + (piL<<3) + (s0L<<2)];
    uint4v qb1 = *(const uint4v*)&zbuf[(1<<9) + (piL<<3) + ((1-s0L)<<2)];
    hh0.u = uint4v{ (qa0.y<<16)|(qa0.x&0xffffu), (qa0.w<<16)|(qa0.z&0xffffu),
                    (qb0.y<<16)|(qb0.x&0xffffu), (qb0.w<<16)|(qb0.z&0xffffu) };
    hl0.u = uint4v{ (qa0.y&0xffff0000u)|(qa0.x>>16), (qa0.w&0xffff0000u)|(qa0.z>>16),
                    (qb0.y&0xffff0000u)|(qb0.x>>16), (qb0.w&0xffff0000u)|(qb0.z>>16) };
    hh1.u = uint4v{ (qa1.y<<16)|(qa1.x&0xffffu), (qa1.w<<16)|(qa1.z&0xffffu),
                    (qb1.y<<16)|(qb1.x&0xffffu), (qb1.w<<16)|(qb1.z&0xffffu) };
    hl1.u = uint4v{ (qa1.y&0xffff0000u)|(qa1.x>>16), (qa1.w&0xffff0000u)|(qa1.z>>16),
                    (qb1.y&0xffff0000u)|(qb1.x>>16), (qb1.w&0xffff0000u)|(qb1.z>>16) };
  }

  // s1 = V @ Wfull + bf1 via MFMA (row 0 only); wave w owns cols 32w..32w+31
  {
    const uint4v* WfHp = (const uint4v*)(ws + WS_WF_H);
    const uint4v* WfLp = (const uint4v*)(ws + WS_WF_L);
    const int nt0 = (w<<1);
    float bf1a = 0.f, bf1b = 0.f;
    if (quad == 0){ bf1a = bf1[c + (w<<5)]; bf1b = bf1[c + (w<<5) + 16]; }
    f32x4 sacc0 = {0.f,0.f,0.f,0.f}, sacc1 = {0.f,0.f,0.f,0.f};
    for (int ks = 0; ks < 4; ++ks){
      U4 vh, vl;
      vh.u = *(const uint4v*)((const char*)lds_Vh + (ks<<6) + (quad<<4));
      vl.u = *(const uint4v*)((const char*)lds_Vl + (ks<<6) + (quad<<4));
      if (c != 0){ vh.u = uint4v{0,0,0,0}; vl.u = uint4v{0,0,0,0}; }
      U4 wh, wl;
      wh.u = WfHp[((ks<<3)+nt0)*64 + lane];
      wl.u = WfLp[((ks<<3)+nt0)*64 + lane];
      sacc0 = mfma16(vh, wh, sacc0);
      sacc0 = mfma16(vh, wl, sacc0);
      sacc0 = mfma16(vl, wh, sacc0);
      wh.u = WfHp[((ks<<3)+nt0+1)*64 + lane];
      wl.u = WfLp[((ks<<3)+nt0+1)*64 + lane];
      sacc1 = mfma16(vh, wh, sacc1);
      sacc1 = mfma16(vh, wl, sacc1);
      sacc1 = mfma16(vl, wh, sacc1);
    }
    if (quad == 0){
      int col0 = c + (w<<5);
      lds_s1[col0]      = sacc0[0] + bf1a;
      lds_s1[col0 + 16] = sacc1[0] + bf1b;
    }
  }
  __syncthreads();  // [Bh3] s1 ready

  // P = h @ Wa (3-pass split), single W buffer;
  // epilogue: out_n = sum_j relu(P+s1)[j]*Wf2[j]
  const uint4v* WaHp = (const uint4v*)(ws + WS_WA_H);
  const uint4v* WaLp = (const uint4v*)(ws + WS_WA_L);
  float s1v[8];
#pragma unroll
  for (int nt = 0; nt < 8; ++nt) s1v[nt] = lds_s1[c + (nt<<4)];
  float outacc[4] = {0.f,0.f,0.f,0.f};
#pragma unroll
  for (int nt = 0; nt < 8; ++nt){
    f32x4 g = {0.f,0.f,0.f,0.f};
    U4 wh, wl;
    wh.u = WaHp[nt*64 + lane];
    wl.u = WaLp[nt*64 + lane];
    g = mfma16(hh0, wh, g); g = mfma16(hh0, wl, g); g = mfma16(hl0, wh, g);
    wh.u = WaHp[(8+nt)*64 + lane];
    wl.u = WaLp[(8+nt)*64 + lane];
    g = mfma16(hh1, wh, g); g = mfma16(hh1, wl, g); g = mfma16(hl1, wh, g);
    float sv = s1v[nt]; float w2 = wf2v[nt];
    outacc[0] += fmaxf(g[0] + sv, 0.f) * w2;
    outacc[1] += fmaxf(g[1] + sv, 0.f) * w2;
    outacc[2] += fmaxf(g[2] + sv, 0.f) * w2;
    outacc[3] += fmaxf(g[3] + sv, 0.f) * w2;
  }
  {
#pragma unroll
    for (int r = 0; r < 4; ++r){
      float v = outacc[r];
      v += __shfl_xor(v, 1); v += __shfl_xor(v, 2);
      v += __shfl_xor(v, 4); v += __shfl_xor(v, 8);
      if (c == 0){
        int row = (w<<4) + (quad<<2) + r;
        if (row < 63) out[item*63 + row] = v + bb2;
      }
    }
  }
}

extern "C" void kernel_launch(void* const* d_in, const int* in_sizes, int n_in,
                              void* d_out, int out_size, void* d_ws, size_t ws_size,
                              hipStream_t stream)
{
  const float* dobs = (const float*)d_in[0];
  const float* sobs = (const float*)d_in[1];
  const float* adj  = (const float*)d_in[2];
  const float* Wdev = (const float*)d_in[3];
  const float* bdev = (const float*)d_in[4];
  const float* Wsrv = (const float*)d_in[5];
  const float* bsrv = (const float*)d_in[6];
  const float* W1   = (const float*)d_in[7];
  const float* b1   = (const float*)d_in[8];
  const float* W2   = (const float*)d_in[9];
  const float* b2   = (const float*)d_in[10];
  const float* W3   = (const float*)d_in[11];
  const float* b3   = (const float*)d_in[12];
  const float* Wf1  = (const float*)d_in[13];
  const float* bf1  = (const float*)d_in[14];
  const float* Wf2  = (const float*)d_in[15];
  const float* bf2  = (const float*)d_in[16];
  float* out = (float*)d_out;
  char* ws = (char*)d_ws;
  int nb = in_sizes[1] / 3;   // batch size (server_obs is B x 3)

  prep_weights<<<dim3(160), dim3(256), 0, stream>>>(Wdev, W1, W2, W3, Wf1, ws);
  pgcn_fused<<<dim3(nb), dim3(256), 0, stream>>>(dobs, sobs, adj, bdev, Wsrv, bsrv,
                                                 b1, b2, b3, bf1, Wf2, bf2, ws, out);
}